// Round 4
// baseline (1007.375 us; speedup 1.0000x reference)
//
#include <hip/hip_runtime.h>
#include <hip/hip_bf16.h>

// R20: 4-node-concurrent gather (k_gather6). Evidence: gather3/5 both sit at
// 3.2-3.4 TB/s, ~60% memory stall, regardless of per-instruction efficiency;
// mean degree 32 means the main loop runs ~1 iteration/node, so per-wave MLP
// is capped at 4 outstanding loads. gather6 processes the wave's 4 nodes
// CONCURRENTLY (edge lists contiguous via counting sort; 5 rowptr loads give
// all bounds): per step 4 independent full-row h loads + 4 edata prefetches
// = 8 loads in flight/wave (2x gather5). Tail lanes clamp to edata[0] (L1
// hit, coef masked 0). 32 f32 accumulators (4 nodes x 8 feats/lane).
// Discriminates latency-bound (expect 60-75us) vs random-access BW wall
// (stay ~90us at 3.3 TB/s -> pivot next round).
// Rest identical to R16: zero-global-atomic counting sort, w15-packed edata,
// h bf16 pre-scaled by dis[src], bf16 intermediates, BN/relu fused in GEMMs.

#define NN 100000
#define NE 3200000
#define INV_N (1.0f/100000.0f)
#define BN_EPS 1e-5f
#define NBK 782            // buckets of 128 nodes
#define NSB 512            // scatter/hist blocks
#define EPB 6250           // edges per scatter/hist block (NSB*EPB == NE)
#define CAPB 6144          // LDS staging per bucket (mean 4092 + 32 sigma)

static __device__ __forceinline__ float bf2f(unsigned short u) {
    if ((u & 0x7f80u) == 0x7f80u) u = 0;          // inf/NaN -> 0 (input scrub)
    union { unsigned int i; float f; } z; z.i = ((unsigned int)u) << 16; return z.f;
}
static __device__ __forceinline__ float scrubf(float v) {
    return (fabsf(v) < 1e30f) ? v : 0.f;
}
static __device__ __forceinline__ unsigned short f2bf(float v) {
    union { float f; unsigned int i; } z; z.f = v;
    unsigned int lsb = (z.i >> 16) & 1u; z.i += 0x7fffu + lsb;
    return (unsigned short)(z.i >> 16);
}
static __device__ __forceinline__ float ld1(const void* p, size_t i, int f) {
    return f ? scrubf(((const float*)p)[i]) : bf2f(((const unsigned short*)p)[i]);
}
static __device__ __forceinline__ float4 ld4(const void* p, size_t g, int f) {
    if (f) { float4 v = ((const float4*)p)[g];
             return make_float4(scrubf(v.x),scrubf(v.y),scrubf(v.z),scrubf(v.w)); }
    ushort4 u = ((const ushort4*)p)[g];
    return make_float4(bf2f(u.x),bf2f(u.y),bf2f(u.z),bf2f(u.w));
}
static __device__ __forceinline__ int getidx(const int* ei, size_t pos, int i64) {
    return i64 ? ei[2*pos] : ei[pos];
}
static __device__ __forceinline__ float blo(unsigned v) {
    union { unsigned u; float f; } z; z.u = v << 16; return z.f;
}
static __device__ __forceinline__ float bhi(unsigned v) {
    union { unsigned u; float f; } z; z.u = v & 0xffff0000u; return z.f;
}
static __device__ __forceinline__ unsigned w15of(unsigned wu) {
    unsigned lsb = (wu >> 17) & 1u;
    return ((wu + 0xFFFFu + lsb) >> 17) & 0x7fffu;
}

// ---------------- detector + sums zero ----------------
__global__ void k_detect2(const unsigned short* __restrict__ x,
                          const int* __restrict__ ei, int* __restrict__ flag,
                          float* __restrict__ sums) {
    __shared__ int cnt[256];
    int tid = threadIdx.x, c = 0;
    for (int i = tid; i < 1024; i += 256) {
        unsigned short u = x[i];
        int ex = (u >> 7) & 0xff;
        if ((u & 0x7fffu) != 0 && (ex >= 0xB0 || ex <= 0x40)) c++;
    }
    cnt[tid] = c; __syncthreads();
    if (tid == 0) { int t = 0; for (int i = 0; i < 256; ++i) t += cnt[i];
                    flag[0] = (t > 64) ? 1 : 0; }
    if (tid == 1) { int nz = 0; for (int i = 1; i < 64; i += 2) nz |= ei[i];
                    flag[1] = (nz == 0) ? 1 : 0; }
    if (tid < 128) { sums[tid]=0.f; sums[128+tid]=0.f; sums[256+tid]=0.f; }
}

// ================= bucket counting sort (no global atomics) =================

__global__ __launch_bounds__(256) void k_hist(const int* __restrict__ flag,
                                              const int* __restrict__ ei,
                                              int* __restrict__ histmat) {
    __shared__ int hh[NBK];
    const int i64 = flag[1];
    const int blk = blockIdx.x, tid = threadIdx.x;
    for (int b = tid; b < NBK; b += 256) hh[b] = 0;
    __syncthreads();
    const size_t e0 = (size_t)blk * EPB;
    for (int e = tid; e < EPB; e += 256) {
        unsigned d = (unsigned)getidx(ei, NE + e0 + e, i64);
        if (d < NN) atomicAdd(&hh[d >> 7], 1);
    }
    __syncthreads();
    for (int b = tid; b < NBK; b += 256) histmat[blk*NBK + b] = hh[b];
}

// per-bucket column scan across the NSB=512 blocks (exclusive), total -> btot
__global__ __launch_bounds__(256) void k_scanA(int* __restrict__ histmat,
                                               int* __restrict__ btot) {
    __shared__ int sd[256];
    const int b = blockIdx.x, t = threadIdx.x;
    int v0 = histmat[(2*t)*NBK + b];
    int v1 = histmat[(2*t+1)*NBK + b];
    int ts = v0 + v1;
    sd[t] = ts; __syncthreads();
    #pragma unroll
    for (int ofs = 1; ofs < 256; ofs <<= 1) {
        int a = (t >= ofs) ? sd[t-ofs] : 0;
        __syncthreads(); sd[t] += a; __syncthreads();
    }
    int excl = sd[t] - ts;
    histmat[(2*t)*NBK + b]   = excl;
    histmat[(2*t+1)*NBK + b] = excl + v0;
    if (t == 255) btot[b] = sd[255];
}

__global__ void k_scanB(const int* __restrict__ btot, int* __restrict__ bstart) {
    __shared__ int sd[1024];
    int t = threadIdx.x;                 // 1024 threads; NBK=782 < 1024
    int v = (t < NBK) ? btot[t] : 0;
    sd[t] = v; __syncthreads();
    #pragma unroll
    for (int ofs = 1; ofs < 1024; ofs <<= 1) {
        int a = (t >= ofs) ? sd[t-ofs] : 0;
        __syncthreads(); sd[t] += a; __syncthreads();
    }
    if (t <= NBK) bstart[t] = sd[t] - v;   // exclusive; bstart[NBK] = total
}

__global__ __launch_bounds__(256) void k_scatter(
    const int* __restrict__ flag, const int* __restrict__ ei,
    const void* __restrict__ ew, const int* __restrict__ histmat,
    const int* __restrict__ bstart, int2* __restrict__ scr) {
    __shared__ int cursor[NBK];
    const int f = flag[0], i64 = flag[1];
    const int blk = blockIdx.x, tid = threadIdx.x;
    for (int b = tid; b < NBK; b += 256)
        cursor[b] = histmat[blk*NBK + b] + bstart[b];
    __syncthreads();
    const size_t e0 = (size_t)blk * EPB;
    for (int e = tid; e < EPB; e += 256) {
        unsigned d = (unsigned)getidx(ei, NE + e0 + e, i64);
        if (d >= NN) continue;
        unsigned s = (unsigned)getidx(ei, e0 + e, i64);
        float w = ld1(ew, e0 + e, f);
        if (s >= NN) { s = 0; w = 0.f; }
        int pos = atomicAdd(&cursor[d >> 7], 1);
        scr[pos] = make_int2((int)(((d & 127u) << 17) | s), __float_as_int(w));
    }
}

// fused node-sort + degree over 128-node buckets; w15 staged in LDS;
// coalesced edata write. Overflow (> CAPB, never here): scattered-write path.
__global__ __launch_bounds__(256) void k_sortdeg(
    const int* __restrict__ bstart, const int2* __restrict__ scr,
    unsigned* __restrict__ edata, int* __restrict__ rowptr, float* __restrict__ dis) {
    __shared__ unsigned sp[CAPB];
    __shared__ unsigned out[CAPB];
    __shared__ unsigned short sww[CAPB];
    __shared__ int cnt[128], scn[128], cur[128];
    __shared__ float degf[128];
    const int b = blockIdx.x, tid = threadIdx.x;
    const int node0 = b * 128;
    const int r0 = bstart[b], r1 = bstart[b+1], n = r1 - r0;
    const bool fit = (n <= CAPB);

    if (tid < 128) { cnt[tid] = 0; degf[tid] = 1.0f; }
    __syncthreads();
    if (fit) {
        for (int j = tid; j < n; j += 256) {
            int2 m = scr[r0 + j];
            sp[j] = (unsigned)m.x;
            sww[j] = (unsigned short)w15of((unsigned)m.y);
            int l = (m.x >> 17) & 127;
            atomicAdd(&cnt[l], 1);
            atomicAdd(&degf[l], __int_as_float(m.y));
        }
    } else {
        for (int j = tid; j < n; j += 256) {
            int2 m = scr[r0 + j];
            int l = (m.x >> 17) & 127;
            atomicAdd(&cnt[l], 1);
            atomicAdd(&degf[l], __int_as_float(m.y));
        }
    }
    __syncthreads();
    if (tid < 128) scn[tid] = cnt[tid];
    __syncthreads();
    #pragma unroll
    for (int ofs = 1; ofs < 128; ofs <<= 1) {
        int a = 0;
        if (tid < 128 && tid >= ofs) a = scn[tid - ofs];
        __syncthreads();
        if (tid < 128) scn[tid] += a;
        __syncthreads();
    }
    if (tid < 128) {
        int excl = scn[tid] - cnt[tid];
        cur[tid] = excl;
        int node = node0 + tid;
        if (node <= NN) rowptr[node] = r0 + excl;
        if (node <  NN) dis[node] = rsqrtf(fmaxf(degf[tid], 1e-12f));
    }
    __syncthreads();
    if (fit) {
        for (int j = tid; j < n; j += 256) {
            unsigned p = sp[j];
            int l = (p >> 17) & 127;
            int pos = atomicAdd(&cur[l], 1);
            out[pos] = (p & 0x1ffffu) | ((unsigned)sww[j] << 17);
        }
        __syncthreads();
        for (int j = tid; j < n; j += 256)           // coalesced linear write
            edata[r0 + j] = out[j];
    } else {
        for (int j = tid; j < n; j += 256) {
            int2 m = scr[r0 + j];
            int l = (m.x >> 17) & 127;
            int pos = atomicAdd(&cur[l], 1);
            edata[r0 + pos] = ((unsigned)m.x & 0x1ffffu) | (w15of((unsigned)m.y) << 17);
        }
    }
}

// gather: wave processes 4 CONSECUTIVE nodes concurrently. 8 edge-slots (g)
// x 8 lanes (l, 16B uint4 slice of the 128B row). Per step: 4 independent
// h loads (one per node) + 4 edata prefetches for next step = 8 loads in
// flight. Tail lanes clamp to edata[0] (coef masked 0; redundant loads are
// L1 hits). rowptr[n+1] is the end for every n (verified incl. bucket
// boundaries and n=NN-1). Epilogue: 3-stage shfl reduce, self+bias in g==0.
__global__ __launch_bounds__(256, 8) void k_gather6(
    const int* __restrict__ flag, const int* __restrict__ rowptr,
    const unsigned* __restrict__ edata, const float* __restrict__ dis,
    const void* __restrict__ bias, const unsigned* __restrict__ h32,
    unsigned* __restrict__ aggB) {
    const int f = flag[0];
    const int node0 = blockIdx.x * 16 + (threadIdx.x >> 6) * 4; // grid NN/16
    const int lane = threadIdx.x & 63;
    const int g = lane >> 3;                               // edge slot 0..7
    const int l = lane & 7;                                // 16B slice 0..7
    const uint4* __restrict__ h4 = (const uint4*)h32;      // row = 8 x uint4

    const int r0 = rowptr[node0+0], r1 = rowptr[node0+1];
    const int r2 = rowptr[node0+2], r3 = rowptr[node0+3];
    const int r4 = rowptr[node0+4];
    const float d0 = dis[node0+0], d1 = dis[node0+1];
    const float d2v = dis[node0+2], d3 = dis[node0+3];

    int mx = max(max(r1-r0, r2-r1), max(r3-r2, r4-r3));
    const int nsteps = (mx + 7) >> 3;

    float a0[8], a1[8], a2[8], a3[8];
    #pragma unroll
    for (int k = 0; k < 8; ++k) { a0[k]=0.f; a1[k]=0.f; a2[k]=0.f; a3[k]=0.f; }

    int i0 = r0 + g, i1 = r1 + g, i2 = r2 + g, i3 = r3 + g;
    unsigned mm0 = edata[i0 < r1 ? i0 : 0];
    unsigned mm1 = edata[i1 < r2 ? i1 : 0];
    unsigned mm2 = edata[i2 < r3 ? i2 : 0];
    unsigned mm3 = edata[i3 < r4 ? i3 : 0];

    for (int s = 0; s < nsteps; ++s) {
        // h loads for current step (4 independent)
        uint4 w0 = h4[(size_t)(mm0 & 0x1ffffu)*8 + l];
        uint4 w1 = h4[(size_t)(mm1 & 0x1ffffu)*8 + l];
        uint4 w2 = h4[(size_t)(mm2 & 0x1ffffu)*8 + l];
        uint4 w3 = h4[(size_t)(mm3 & 0x1ffffu)*8 + l];
        float c0 = (i0 < r1) ? __int_as_float((int)(mm0 & 0xFFFE0000u)) * d0  : 0.f;
        float c1 = (i1 < r2) ? __int_as_float((int)(mm1 & 0xFFFE0000u)) * d1  : 0.f;
        float c2 = (i2 < r3) ? __int_as_float((int)(mm2 & 0xFFFE0000u)) * d2v : 0.f;
        float c3 = (i3 < r4) ? __int_as_float((int)(mm3 & 0xFFFE0000u)) * d3  : 0.f;
        // prefetch next step's edata (4 independent; safe clamp to 0)
        i0 += 8; i1 += 8; i2 += 8; i3 += 8;
        mm0 = edata[i0 < r1 ? i0 : 0];
        mm1 = edata[i1 < r2 ? i1 : 0];
        mm2 = edata[i2 < r3 ? i2 : 0];
        mm3 = edata[i3 < r4 ? i3 : 0];
        {   const unsigned ww[4] = {w0.x, w0.y, w0.z, w0.w};
            #pragma unroll
            for (int t = 0; t < 4; ++t) {
                a0[2*t]   = fmaf(c0, blo(ww[t]), a0[2*t]);
                a0[2*t+1] = fmaf(c0, bhi(ww[t]), a0[2*t+1]);
            } }
        {   const unsigned ww[4] = {w1.x, w1.y, w1.z, w1.w};
            #pragma unroll
            for (int t = 0; t < 4; ++t) {
                a1[2*t]   = fmaf(c1, blo(ww[t]), a1[2*t]);
                a1[2*t+1] = fmaf(c1, bhi(ww[t]), a1[2*t+1]);
            } }
        {   const unsigned ww[4] = {w2.x, w2.y, w2.z, w2.w};
            #pragma unroll
            for (int t = 0; t < 4; ++t) {
                a2[2*t]   = fmaf(c2, blo(ww[t]), a2[2*t]);
                a2[2*t+1] = fmaf(c2, bhi(ww[t]), a2[2*t+1]);
            } }
        {   const unsigned ww[4] = {w3.x, w3.y, w3.z, w3.w};
            #pragma unroll
            for (int t = 0; t < 4; ++t) {
                a3[2*t]   = fmaf(c3, blo(ww[t]), a3[2*t]);
                a3[2*t+1] = fmaf(c3, bhi(ww[t]), a3[2*t+1]);
            } }
    }

    // reduce across the 8 edge slots (lane strides 8,16,32)
    #pragma unroll
    for (int k = 0; k < 8; ++k) {
        a0[k] += __shfl_xor(a0[k], 8);  a0[k] += __shfl_xor(a0[k], 16); a0[k] += __shfl_xor(a0[k], 32);
        a1[k] += __shfl_xor(a1[k], 8);  a1[k] += __shfl_xor(a1[k], 16); a1[k] += __shfl_xor(a1[k], 32);
        a2[k] += __shfl_xor(a2[k], 8);  a2[k] += __shfl_xor(a2[k], 16); a2[k] += __shfl_xor(a2[k], 32);
        a3[k] += __shfl_xor(a3[k], 8);  a3[k] += __shfl_xor(a3[k], 16); a3[k] += __shfl_xor(a3[k], 32);
    }

    if (g == 0) {
        float bb_[8];
        #pragma unroll
        for (int t = 0; t < 8; ++t) bb_[t] = ld1(bias, l*8 + t, f);
        {   uint4 hv = h4[(size_t)(node0+0)*8 + l];
            const unsigned hw[4] = {hv.x, hv.y, hv.z, hv.w};
            uint4 o;
            float s0 = a0[0]+bb_[0]+d0*blo(hw[0]), s1 = a0[1]+bb_[1]+d0*bhi(hw[0]);
            float s2 = a0[2]+bb_[2]+d0*blo(hw[1]), s3 = a0[3]+bb_[3]+d0*bhi(hw[1]);
            float s4 = a0[4]+bb_[4]+d0*blo(hw[2]), s5 = a0[5]+bb_[5]+d0*bhi(hw[2]);
            float s6 = a0[6]+bb_[6]+d0*blo(hw[3]), s7 = a0[7]+bb_[7]+d0*bhi(hw[3]);
            o.x = (unsigned)f2bf(s0)|((unsigned)f2bf(s1)<<16);
            o.y = (unsigned)f2bf(s2)|((unsigned)f2bf(s3)<<16);
            o.z = (unsigned)f2bf(s4)|((unsigned)f2bf(s5)<<16);
            o.w = (unsigned)f2bf(s6)|((unsigned)f2bf(s7)<<16);
            *(uint4*)&aggB[(size_t)(node0+0)*32 + l*4] = o; }
        {   uint4 hv = h4[(size_t)(node0+1)*8 + l];
            const unsigned hw[4] = {hv.x, hv.y, hv.z, hv.w};
            uint4 o;
            float s0 = a1[0]+bb_[0]+d1*blo(hw[0]), s1 = a1[1]+bb_[1]+d1*bhi(hw[0]);
            float s2 = a1[2]+bb_[2]+d1*blo(hw[1]), s3 = a1[3]+bb_[3]+d1*bhi(hw[1]);
            float s4 = a1[4]+bb_[4]+d1*blo(hw[2]), s5 = a1[5]+bb_[5]+d1*bhi(hw[2]);
            float s6 = a1[6]+bb_[6]+d1*blo(hw[3]), s7 = a1[7]+bb_[7]+d1*bhi(hw[3]);
            o.x = (unsigned)f2bf(s0)|((unsigned)f2bf(s1)<<16);
            o.y = (unsigned)f2bf(s2)|((unsigned)f2bf(s3)<<16);
            o.z = (unsigned)f2bf(s4)|((unsigned)f2bf(s5)<<16);
            o.w = (unsigned)f2bf(s6)|((unsigned)f2bf(s7)<<16);
            *(uint4*)&aggB[(size_t)(node0+1)*32 + l*4] = o; }
        {   uint4 hv = h4[(size_t)(node0+2)*8 + l];
            const unsigned hw[4] = {hv.x, hv.y, hv.z, hv.w};
            uint4 o;
            float s0 = a2[0]+bb_[0]+d2v*blo(hw[0]), s1 = a2[1]+bb_[1]+d2v*bhi(hw[0]);
            float s2 = a2[2]+bb_[2]+d2v*blo(hw[1]), s3 = a2[3]+bb_[3]+d2v*bhi(hw[1]);
            float s4 = a2[4]+bb_[4]+d2v*blo(hw[2]), s5 = a2[5]+bb_[5]+d2v*bhi(hw[2]);
            float s6 = a2[6]+bb_[6]+d2v*blo(hw[3]), s7 = a2[7]+bb_[7]+d2v*bhi(hw[3]);
            o.x = (unsigned)f2bf(s0)|((unsigned)f2bf(s1)<<16);
            o.y = (unsigned)f2bf(s2)|((unsigned)f2bf(s3)<<16);
            o.z = (unsigned)f2bf(s4)|((unsigned)f2bf(s5)<<16);
            o.w = (unsigned)f2bf(s6)|((unsigned)f2bf(s7)<<16);
            *(uint4*)&aggB[(size_t)(node0+2)*32 + l*4] = o; }
        {   uint4 hv = h4[(size_t)(node0+3)*8 + l];
            const unsigned hw[4] = {hv.x, hv.y, hv.z, hv.w};
            uint4 o;
            float s0 = a3[0]+bb_[0]+d3*blo(hw[0]), s1 = a3[1]+bb_[1]+d3*bhi(hw[0]);
            float s2 = a3[2]+bb_[2]+d3*blo(hw[1]), s3 = a3[3]+bb_[3]+d3*bhi(hw[1]);
            float s4 = a3[4]+bb_[4]+d3*blo(hw[2]), s5 = a3[5]+bb_[5]+d3*bhi(hw[2]);
            float s6 = a3[6]+bb_[6]+d3*blo(hw[3]), s7 = a3[7]+bb_[7]+d3*bhi(hw[3]);
            o.x = (unsigned)f2bf(s0)|((unsigned)f2bf(s1)<<16);
            o.y = (unsigned)f2bf(s2)|((unsigned)f2bf(s3)<<16);
            o.z = (unsigned)f2bf(s4)|((unsigned)f2bf(s5)<<16);
            o.w = (unsigned)f2bf(s6)|((unsigned)f2bf(s7)<<16);
            *(uint4*)&aggB[(size_t)(node0+3)*32 + l*4] = o; }
    }
}

// ================= dense kernels =================

__global__ __launch_bounds__(256) void k_gemm1(
    const int* __restrict__ flag, const void* __restrict__ x,
    const void* __restrict__ W, const void* __restrict__ bias,
    const float* __restrict__ dis, unsigned short* __restrict__ h_out) {
    __shared__ __align__(16) float ws[128*64];
    __shared__ __align__(16) float xs[64*64];
    const int f = flag[0];
    const int tid = threadIdx.x;
    const int rowbase = blockIdx.x * 64;
    #pragma unroll
    for (int it = 0; it < 8; ++it) {
        int g = it*256 + tid;
        float4 v = ld4(W, g, f);
        int b = g*4;
        ws[b]=v.x; ws[b+1]=v.y; ws[b+2]=v.z; ws[b+3]=v.w;
    }
    const int tr = (tid >> 4) << 2;
    const int tc = (tid & 15) << 2;
    const int row = tid & 63;
    const int grow = rowbase + row;
    const bool valid = grow < NN;
    float acc[4][4] = {};
    for (int half = 0; half < 2; ++half) {
        __syncthreads();
        #pragma unroll
        for (int it = 0; it < 4; ++it) {
            int f4 = (tid >> 6) + it*4;
            int kl = f4*4;
            float4 v = make_float4(0,0,0,0);
            if (valid) v = ld4(x, (size_t)grow*32 + half*16 + f4, f);
            xs[(kl+0)*64+row]=v.x; xs[(kl+1)*64+row]=v.y;
            xs[(kl+2)*64+row]=v.z; xs[(kl+3)*64+row]=v.w;
        }
        __syncthreads();
        #pragma unroll 8
        for (int k = 0; k < 64; ++k) {
            const float4 av = *(const float4*)&xs[k*64 + tr];
            const float4 wv = *(const float4*)&ws[(half*64 + k)*64 + tc];
            const float aa[4] = {av.x, av.y, av.z, av.w};
            const float ww[4] = {wv.x, wv.y, wv.z, wv.w};
            #pragma unroll
            for (int i = 0; i < 4; ++i)
                #pragma unroll
                for (int j = 0; j < 4; ++j)
                    acc[i][j] = fmaf(aa[i], ww[j], acc[i][j]);
        }
    }
    #pragma unroll
    for (int i = 0; i < 4; ++i) {
        int r = rowbase + tr + i;
        if (r < NN) {
            float hm = dis[r];
            ushort4 hv = make_ushort4(f2bf(acc[i][0]*hm), f2bf(acc[i][1]*hm),
                                      f2bf(acc[i][2]*hm), f2bf(acc[i][3]*hm));
            *(ushort4*)&h_out[(size_t)r*64 + tc] = hv;
        }
    }
}

// BN column stats over bf16 tensor (uint2 = 4 features); 512 blocks
__global__ __launch_bounds__(256) void k_bnstats_bf(const uint2* __restrict__ src,
                                                    float* __restrict__ sumout, int relu) {
    const int tid = threadIdx.x;
    float s0=0,s1=0,s2=0,s3=0, q0=0,q1=0,q2=0,q3=0;
    for (int g = blockIdx.x*256 + tid; g < NN*16; g += 512*256) {
        uint2 u = src[g];
        float vx = blo(u.x), vy = bhi(u.x), vz = blo(u.y), vw = bhi(u.y);
        if (relu) { vx=fmaxf(vx,0.f); vy=fmaxf(vy,0.f);
                    vz=fmaxf(vz,0.f); vw=fmaxf(vw,0.f); }
        s0+=vx; q0+=vx*vx; s1+=vy; q1+=vy*vy;
        s2+=vz; q2+=vz*vz; s3+=vw; q3+=vw*vw;
    }
    __shared__ float ls[1024], lq[1024];
    ls[tid*4+0]=s0; ls[tid*4+1]=s1; ls[tid*4+2]=s2; ls[tid*4+3]=s3;
    lq[tid*4+0]=q0; lq[tid*4+1]=q1; lq[tid*4+2]=q2; lq[tid*4+3]=q3;
    __syncthreads();
    if (tid < 64) {
        int grp = tid >> 2, k = tid & 3;
        float s = 0.f, q = 0.f;
        #pragma unroll
        for (int m = 0; m < 16; ++m) {
            int idx = (grp + 16*m)*4 + k;
            s += ls[idx]; q += lq[idx];
        }
        unsafeAtomicAdd(&sumout[tid], s);
        unsafeAtomicAdd(&sumout[64+tid], q);
    }
}

// 64x64 GEMM, bf16 input with fused BN (+relu).
template<bool RELU, bool AGG>
__global__ __launch_bounds__(256) void k_gemm64(
    const int* __restrict__ flag, const unsigned short* __restrict__ in,
    const void* __restrict__ W, const void* __restrict__ bias,
    const void* __restrict__ g, const void* __restrict__ bb,
    const float* __restrict__ insums, const float* __restrict__ dis,
    unsigned short* __restrict__ out_bf, float* __restrict__ outsums) {
    __shared__ __align__(16) float ws[64*64];
    __shared__ __align__(16) float xs[64*64];
    __shared__ float sc[64], sh[64];
    const int f = flag[0];
    const int tid = threadIdx.x;
    const int rowbase = blockIdx.x * 64;
    if (tid < 64) {
        float mean = insums[tid] * INV_N;
        float var  = fmaxf(insums[64+tid] * INV_N - mean*mean, 0.f);
        float s = ld1(g, tid, f) * rsqrtf(var + BN_EPS);
        sc[tid] = s;
        sh[tid] = ld1(bb, tid, f) - mean*s;
    }
    #pragma unroll
    for (int it = 0; it < 4; ++it) {
        int gi = it*256 + tid;
        float4 v = ld4(W, gi, f);
        int b = gi*4;
        ws[b]=v.x; ws[b+1]=v.y; ws[b+2]=v.z; ws[b+3]=v.w;
    }
    __syncthreads();
    {
        int row = tid & 63;
        int grow = rowbase + row;
        bool valid = grow < NN;
        #pragma unroll
        for (int it = 0; it < 4; ++it) {
            int f4 = (tid >> 6) + it*4;
            int k = f4*4;
            float a0=0,a1=0,a2=0,a3=0;
            if (valid) {
                ushort4 u = *(const ushort4*)&in[(size_t)grow*64 + k];
                a0=bf2f(u.x); a1=bf2f(u.y); a2=bf2f(u.z); a3=bf2f(u.w);
            }
            if (RELU) { a0=fmaxf(a0,0.f); a1=fmaxf(a1,0.f); a2=fmaxf(a2,0.f); a3=fmaxf(a3,0.f); }
            a0 = a0*sc[k+0]+sh[k+0]; a1 = a1*sc[k+1]+sh[k+1];
            a2 = a2*sc[k+2]+sh[k+2]; a3 = a3*sc[k+3]+sh[k+3];
            xs[(k+0)*64+row]=a0; xs[(k+1)*64+row]=a1;
            xs[(k+2)*64+row]=a2; xs[(k+3)*64+row]=a3;
        }
    }
    __syncthreads();
    const int tr = (tid >> 4) << 2;
    const int tc = (tid & 15) << 2;
    float acc[4][4] = {};
    #pragma unroll 8
    for (int k = 0; k < 64; ++k) {
        const float4 av = *(const float4*)&xs[k*64 + tr];
        const float4 wv = *(const float4*)&ws[k*64 + tc];
        const float aa[4] = {av.x, av.y, av.z, av.w};
        const float ww[4] = {wv.x, wv.y, wv.z, wv.w};
        #pragma unroll
        for (int i = 0; i < 4; ++i)
            #pragma unroll
            for (int j = 0; j < 4; ++j)
                acc[i][j] = fmaf(aa[i], ww[j], acc[i][j]);
    }
    float bc[4];
    #pragma unroll
    for (int j = 0; j < 4; ++j) bc[j] = ld1(bias, tc+j, f);
    if (AGG) {
        #pragma unroll
        for (int i = 0; i < 4; ++i) {
            int r = rowbase + tr + i;
            if (r < NN) {
                float hm = dis[r];
                ushort4 hv = make_ushort4(f2bf(acc[i][0]*hm), f2bf(acc[i][1]*hm),
                                          f2bf(acc[i][2]*hm), f2bf(acc[i][3]*hm));
                *(ushort4*)&out_bf[(size_t)r*64 + tc] = hv;
            }
        }
    } else {
        float ps[4] = {0,0,0,0}, pq[4] = {0,0,0,0};
        #pragma unroll
        for (int i = 0; i < 4; ++i) {
            int r = rowbase + tr + i;
            if (r < NN) {
                float y0 = acc[i][0]+bc[0], y1 = acc[i][1]+bc[1];
                float y2 = acc[i][2]+bc[2], y3 = acc[i][3]+bc[3];
                *(ushort4*)&out_bf[(size_t)r*64 + tc] =
                    make_ushort4(f2bf(y0), f2bf(y1), f2bf(y2), f2bf(y3));
                ps[0]+=y0; ps[1]+=y1; ps[2]+=y2; ps[3]+=y3;
                pq[0]+=y0*y0; pq[1]+=y1*y1; pq[2]+=y2*y2; pq[3]+=y3*y3;
            }
        }
        __syncthreads();
        int grp = tid >> 4;
        #pragma unroll
        for (int j = 0; j < 4; ++j) { xs[grp*64 + tc+j] = ps[j]; ws[grp*64 + tc+j] = pq[j]; }
        __syncthreads();
        if (tid < 64) {
            float s = 0.f, q = 0.f;
            #pragma unroll
            for (int g2 = 0; g2 < 16; ++g2) { s += xs[g2*64+tid]; q += ws[g2*64+tid]; }
            unsafeAtomicAdd(&outsums[tid], s);
            unsafeAtomicAdd(&outsums[64+tid], q);
        }
    }
}

// final: out = bn3(y3_bf16) @ lin2_W + lin2_b
__global__ __launch_bounds__(256) void k_final(
    const int* __restrict__ flag, const unsigned short* __restrict__ y3,
    const void* __restrict__ g, const void* __restrict__ bb,
    const float* __restrict__ sums, const void* __restrict__ w2,
    const void* __restrict__ b2, void* __restrict__ out) {
    __shared__ __align__(16) float tile[64*64];
    __shared__ float wp[64], tv[64];
    const int f = flag[0];
    const int tid = threadIdx.x;
    const int base = blockIdx.x * 64;
    if (tid < 64) {
        float mean = sums[tid] * INV_N;
        float var  = fmaxf(sums[64+tid] * INV_N - mean*mean, 0.f);
        float s = ld1(g, tid, f) * rsqrtf(var + BN_EPS);
        float t = ld1(bb, tid, f) - mean*s;
        float w = ld1(w2, tid, f);
        wp[tid] = s*w; tv[tid] = t*w;
    }
    #pragma unroll
    for (int it = 0; it < 4; ++it) {
        int i4 = it*256 + tid;
        int row = i4 >> 4, c4 = (i4 & 15)*4;
        float4 v = make_float4(0,0,0,0);
        if (base + row < NN) {
            ushort4 u = *(const ushort4*)&y3[(size_t)(base+row)*64 + c4];
            v = make_float4(bf2f(u.x), bf2f(u.y), bf2f(u.z), bf2f(u.w));
        }
        *(float4*)&tile[row*64 + c4] = v;
    }
    __syncthreads();
    if (tid < 64 && base + tid < NN) {
        float a = ld1(b2, 0, f);
        #pragma unroll
        for (int c = 0; c < 64; ++c) a += tv[c];
        #pragma unroll
        for (int cc = 0; cc < 64; ++cc) {
            int c = (cc + tid) & 63;
            a += tile[tid*64 + c] * wp[c];
        }
        if (f) ((float*)out)[base + tid] = a;
        else   ((unsigned short*)out)[base + tid] = f2bf(a);
    }
}

extern "C" void kernel_launch(void* const* d_in, const int* in_sizes, int n_in,
                              void* d_out, int out_size, void* d_ws, size_t ws_size,
                              hipStream_t stream) {
    const unsigned short* x = (const unsigned short*)d_in[0];
    const void* ew  = d_in[1];
    const void* W1  = d_in[2];
    const void* b1  = d_in[3];
    const void* W2  = d_in[4];
    const void* b2  = d_in[5];
    const void* l1W = d_in[6];
    const void* l1b = d_in[7];
    const void* l2W = d_in[8];
    const void* l2b = d_in[9];
    const void* g1  = d_in[10];
    const void* bb1 = d_in[11];
    const void* g2  = d_in[12];
    const void* bb2 = d_in[13];
    const void* g3  = d_in[14];
    const void* bb3 = d_in[15];
    const int* eidx = (const int*)d_in[16];

    // layout (float idx): flag 0, sums 16, dis 400;
    // region 100400..6500400: scr(int2) during preprocessing, then aggB (bf16)
    // hbuf(bf16) 6500400..9700400, histmat/rowptr 9700400, btot 10500656,
    // bstart 10502224, edata 10503792..13703792. Need 54.8 MB (proven).
    int*   flag = (int*)d_ws;
    float* wsf  = (float*)d_ws;
    float* sums = wsf + 16;
    float* dis  = wsf + 400;
    unsigned*       aggB = (unsigned*)(wsf + 100400);
    unsigned short* aggS = (unsigned short*)(wsf + 100400);
    unsigned short* hbuf = (unsigned short*)(wsf + 6500400);
    int*      histmat = (int*)(wsf + 9700400);
    int*      rowptr2 = histmat;
    int*      btot    = (int*)(wsf + 10500656);
    int*      bstart  = (int*)(wsf + 10502224);
    unsigned* edata   = (unsigned*)(wsf + 10503792);
    int2*     scr     = (int2*)(wsf + 100400);
    const size_t NEED = (size_t)13703792 * 4;
    if (ws_size < NEED) return;

    k_detect2  <<<1, 256, 0, stream>>>(x, eidx, flag, sums);
    k_hist     <<<NSB, 256, 0, stream>>>(flag, eidx, histmat);
    k_scanA    <<<NBK, 256, 0, stream>>>(histmat, btot);
    k_scanB    <<<1, 1024, 0, stream>>>(btot, bstart);
    k_scatter  <<<NSB, 256, 0, stream>>>(flag, eidx, ew, histmat, bstart, scr);
    k_sortdeg  <<<NBK, 256, 0, stream>>>(bstart, scr, edata, rowptr2, dis);
    // layer 1
    k_gemm1    <<<1563, 256, 0, stream>>>(flag, x, W1, b1, dis, hbuf);
    k_gather6  <<<NN/16, 256, 0, stream>>>(flag, rowptr2, edata, dis, b1,
                                           (const unsigned*)hbuf, aggB);
    k_bnstats_bf<<<512, 256, 0, stream>>>((const uint2*)aggB, sums + 0, 1);
    // layer 2
    k_gemm64<true, true><<<1563, 256, 0, stream>>>(flag, aggS, W2, b2, g1, bb1,
                                                   sums + 0, dis, hbuf, nullptr);
    k_gather6  <<<NN/16, 256, 0, stream>>>(flag, rowptr2, edata, dis, b2,
                                           (const unsigned*)hbuf, aggB);
    k_bnstats_bf<<<512, 256, 0, stream>>>((const uint2*)aggB, sums + 128, 0);
    // lin1 (+ bn3 stats), y3 bf16 in place over agg2
    k_gemm64<false, false><<<1563, 256, 0, stream>>>(flag, aggS, l1W, l1b, g2, bb2,
                                                     sums + 128, dis, aggS, sums + 256);
    k_final    <<<1563, 256, 0, stream>>>(flag, aggS, g3, bb3, sums + 256, l2W, l2b, d_out);
}

// Round 5
// 602.036 us; speedup vs baseline: 1.6733x; 1.6733x over previous
//
#include <hip/hip_runtime.h>
#include <hip/hip_bf16.h>

// R21: spill-free pipelined 4-node gather (k_gather7).
// R20's gather6 proved the fabric does 4.4 TB/s (vs gather3/5's 3.3) but
// __launch_bounds__(256,8) capped VGPR at 64 -> accumulators spilled to
// scratch (WRITE_SIZE 12.5MB -> 537MB, VALU 14%, 294us). gather7 keeps the
// 4-node-concurrent structure with launch_bounds(256,4) (128 VGPR, ~110
// used) and a 2-deep software pipeline: edata prefetched 2 steps ahead,
// h-rows 1 step ahead, so step s's FMA consumes h issued a full iteration
// earlier. 8 loads continuously in flight per wave, no dependent stalls.
// Verify: WRITE back to ~12.5MB, FETCH ~300MB. If >=90us with clean
// counters -> access-pattern wall; pivot to non-gather kernels.
// Rest identical to R16: zero-global-atomic counting sort, w15-packed edata,
// h bf16 pre-scaled by dis[src], bf16 intermediates, BN/relu fused in GEMMs.

#define NN 100000
#define NE 3200000
#define INV_N (1.0f/100000.0f)
#define BN_EPS 1e-5f
#define NBK 782            // buckets of 128 nodes
#define NSB 512            // scatter/hist blocks
#define EPB 6250           // edges per scatter/hist block (NSB*EPB == NE)
#define CAPB 6144          // LDS staging per bucket (mean 4092 + 32 sigma)

static __device__ __forceinline__ float bf2f(unsigned short u) {
    if ((u & 0x7f80u) == 0x7f80u) u = 0;          // inf/NaN -> 0 (input scrub)
    union { unsigned int i; float f; } z; z.i = ((unsigned int)u) << 16; return z.f;
}
static __device__ __forceinline__ float scrubf(float v) {
    return (fabsf(v) < 1e30f) ? v : 0.f;
}
static __device__ __forceinline__ unsigned short f2bf(float v) {
    union { float f; unsigned int i; } z; z.f = v;
    unsigned int lsb = (z.i >> 16) & 1u; z.i += 0x7fffu + lsb;
    return (unsigned short)(z.i >> 16);
}
static __device__ __forceinline__ float ld1(const void* p, size_t i, int f) {
    return f ? scrubf(((const float*)p)[i]) : bf2f(((const unsigned short*)p)[i]);
}
static __device__ __forceinline__ float4 ld4(const void* p, size_t g, int f) {
    if (f) { float4 v = ((const float4*)p)[g];
             return make_float4(scrubf(v.x),scrubf(v.y),scrubf(v.z),scrubf(v.w)); }
    ushort4 u = ((const ushort4*)p)[g];
    return make_float4(bf2f(u.x),bf2f(u.y),bf2f(u.z),bf2f(u.w));
}
static __device__ __forceinline__ int getidx(const int* ei, size_t pos, int i64) {
    return i64 ? ei[2*pos] : ei[pos];
}
static __device__ __forceinline__ float blo(unsigned v) {
    union { unsigned u; float f; } z; z.u = v << 16; return z.f;
}
static __device__ __forceinline__ float bhi(unsigned v) {
    union { unsigned u; float f; } z; z.u = v & 0xffff0000u; return z.f;
}
static __device__ __forceinline__ unsigned w15of(unsigned wu) {
    unsigned lsb = (wu >> 17) & 1u;
    return ((wu + 0xFFFFu + lsb) >> 17) & 0x7fffu;
}

// ---------------- detector + sums zero ----------------
__global__ void k_detect2(const unsigned short* __restrict__ x,
                          const int* __restrict__ ei, int* __restrict__ flag,
                          float* __restrict__ sums) {
    __shared__ int cnt[256];
    int tid = threadIdx.x, c = 0;
    for (int i = tid; i < 1024; i += 256) {
        unsigned short u = x[i];
        int ex = (u >> 7) & 0xff;
        if ((u & 0x7fffu) != 0 && (ex >= 0xB0 || ex <= 0x40)) c++;
    }
    cnt[tid] = c; __syncthreads();
    if (tid == 0) { int t = 0; for (int i = 0; i < 256; ++i) t += cnt[i];
                    flag[0] = (t > 64) ? 1 : 0; }
    if (tid == 1) { int nz = 0; for (int i = 1; i < 64; i += 2) nz |= ei[i];
                    flag[1] = (nz == 0) ? 1 : 0; }
    if (tid < 128) { sums[tid]=0.f; sums[128+tid]=0.f; sums[256+tid]=0.f; }
}

// ================= bucket counting sort (no global atomics) =================

__global__ __launch_bounds__(256) void k_hist(const int* __restrict__ flag,
                                              const int* __restrict__ ei,
                                              int* __restrict__ histmat) {
    __shared__ int hh[NBK];
    const int i64 = flag[1];
    const int blk = blockIdx.x, tid = threadIdx.x;
    for (int b = tid; b < NBK; b += 256) hh[b] = 0;
    __syncthreads();
    const size_t e0 = (size_t)blk * EPB;
    for (int e = tid; e < EPB; e += 256) {
        unsigned d = (unsigned)getidx(ei, NE + e0 + e, i64);
        if (d < NN) atomicAdd(&hh[d >> 7], 1);
    }
    __syncthreads();
    for (int b = tid; b < NBK; b += 256) histmat[blk*NBK + b] = hh[b];
}

// per-bucket column scan across the NSB=512 blocks (exclusive), total -> btot
__global__ __launch_bounds__(256) void k_scanA(int* __restrict__ histmat,
                                               int* __restrict__ btot) {
    __shared__ int sd[256];
    const int b = blockIdx.x, t = threadIdx.x;
    int v0 = histmat[(2*t)*NBK + b];
    int v1 = histmat[(2*t+1)*NBK + b];
    int ts = v0 + v1;
    sd[t] = ts; __syncthreads();
    #pragma unroll
    for (int ofs = 1; ofs < 256; ofs <<= 1) {
        int a = (t >= ofs) ? sd[t-ofs] : 0;
        __syncthreads(); sd[t] += a; __syncthreads();
    }
    int excl = sd[t] - ts;
    histmat[(2*t)*NBK + b]   = excl;
    histmat[(2*t+1)*NBK + b] = excl + v0;
    if (t == 255) btot[b] = sd[255];
}

__global__ void k_scanB(const int* __restrict__ btot, int* __restrict__ bstart) {
    __shared__ int sd[1024];
    int t = threadIdx.x;                 // 1024 threads; NBK=782 < 1024
    int v = (t < NBK) ? btot[t] : 0;
    sd[t] = v; __syncthreads();
    #pragma unroll
    for (int ofs = 1; ofs < 1024; ofs <<= 1) {
        int a = (t >= ofs) ? sd[t-ofs] : 0;
        __syncthreads(); sd[t] += a; __syncthreads();
    }
    if (t <= NBK) bstart[t] = sd[t] - v;   // exclusive; bstart[NBK] = total
}

__global__ __launch_bounds__(256) void k_scatter(
    const int* __restrict__ flag, const int* __restrict__ ei,
    const void* __restrict__ ew, const int* __restrict__ histmat,
    const int* __restrict__ bstart, int2* __restrict__ scr) {
    __shared__ int cursor[NBK];
    const int f = flag[0], i64 = flag[1];
    const int blk = blockIdx.x, tid = threadIdx.x;
    for (int b = tid; b < NBK; b += 256)
        cursor[b] = histmat[blk*NBK + b] + bstart[b];
    __syncthreads();
    const size_t e0 = (size_t)blk * EPB;
    for (int e = tid; e < EPB; e += 256) {
        unsigned d = (unsigned)getidx(ei, NE + e0 + e, i64);
        if (d >= NN) continue;
        unsigned s = (unsigned)getidx(ei, e0 + e, i64);
        float w = ld1(ew, e0 + e, f);
        if (s >= NN) { s = 0; w = 0.f; }
        int pos = atomicAdd(&cursor[d >> 7], 1);
        scr[pos] = make_int2((int)(((d & 127u) << 17) | s), __float_as_int(w));
    }
}

// fused node-sort + degree over 128-node buckets; w15 staged in LDS;
// coalesced edata write. Overflow (> CAPB, never here): scattered-write path.
__global__ __launch_bounds__(256) void k_sortdeg(
    const int* __restrict__ bstart, const int2* __restrict__ scr,
    unsigned* __restrict__ edata, int* __restrict__ rowptr, float* __restrict__ dis) {
    __shared__ unsigned sp[CAPB];
    __shared__ unsigned out[CAPB];
    __shared__ unsigned short sww[CAPB];
    __shared__ int cnt[128], scn[128], cur[128];
    __shared__ float degf[128];
    const int b = blockIdx.x, tid = threadIdx.x;
    const int node0 = b * 128;
    const int r0 = bstart[b], r1 = bstart[b+1], n = r1 - r0;
    const bool fit = (n <= CAPB);

    if (tid < 128) { cnt[tid] = 0; degf[tid] = 1.0f; }
    __syncthreads();
    if (fit) {
        for (int j = tid; j < n; j += 256) {
            int2 m = scr[r0 + j];
            sp[j] = (unsigned)m.x;
            sww[j] = (unsigned short)w15of((unsigned)m.y);
            int l = (m.x >> 17) & 127;
            atomicAdd(&cnt[l], 1);
            atomicAdd(&degf[l], __int_as_float(m.y));
        }
    } else {
        for (int j = tid; j < n; j += 256) {
            int2 m = scr[r0 + j];
            int l = (m.x >> 17) & 127;
            atomicAdd(&cnt[l], 1);
            atomicAdd(&degf[l], __int_as_float(m.y));
        }
    }
    __syncthreads();
    if (tid < 128) scn[tid] = cnt[tid];
    __syncthreads();
    #pragma unroll
    for (int ofs = 1; ofs < 128; ofs <<= 1) {
        int a = 0;
        if (tid < 128 && tid >= ofs) a = scn[tid - ofs];
        __syncthreads();
        if (tid < 128) scn[tid] += a;
        __syncthreads();
    }
    if (tid < 128) {
        int excl = scn[tid] - cnt[tid];
        cur[tid] = excl;
        int node = node0 + tid;
        if (node <= NN) rowptr[node] = r0 + excl;
        if (node <  NN) dis[node] = rsqrtf(fmaxf(degf[tid], 1e-12f));
    }
    __syncthreads();
    if (fit) {
        for (int j = tid; j < n; j += 256) {
            unsigned p = sp[j];
            int l = (p >> 17) & 127;
            int pos = atomicAdd(&cur[l], 1);
            out[pos] = (p & 0x1ffffu) | ((unsigned)sww[j] << 17);
        }
        __syncthreads();
        for (int j = tid; j < n; j += 256)           // coalesced linear write
            edata[r0 + j] = out[j];
    } else {
        for (int j = tid; j < n; j += 256) {
            int2 m = scr[r0 + j];
            int l = (m.x >> 17) & 127;
            int pos = atomicAdd(&cur[l], 1);
            edata[r0 + pos] = ((unsigned)m.x & 0x1ffffu) | (w15of((unsigned)m.y) << 17);
        }
    }
}

// gather: wave = 4 consecutive nodes concurrently, 8 edge-slots (g) x 8
// lanes (l = 16B uint4 slice of the 128B row). 2-deep pipeline: edata
// prefetched 2 steps ahead, h 1 step ahead; FMA of step s uses h issued a
// full iteration earlier. Tail lanes clamp to edata[0] (coef masked 0).
// launch_bounds(256,4): 128 VGPR budget, ~110 used, NO spills (R20 lesson).
__global__ __launch_bounds__(256, 4) void k_gather7(
    const int* __restrict__ flag, const int* __restrict__ rowptr,
    const unsigned* __restrict__ edata, const float* __restrict__ dis,
    const void* __restrict__ bias, const unsigned* __restrict__ h32,
    unsigned* __restrict__ aggB) {
    const int f = flag[0];
    const int node0 = blockIdx.x * 16 + (threadIdx.x >> 6) * 4; // grid NN/16
    const int lane = threadIdx.x & 63;
    const int g = lane >> 3;                               // edge slot 0..7
    const int l = lane & 7;                                // 16B slice 0..7
    const uint4* __restrict__ h4 = (const uint4*)h32;      // row = 8 x uint4

    const int r0 = rowptr[node0+0], r1 = rowptr[node0+1];
    const int r2 = rowptr[node0+2], r3 = rowptr[node0+3];
    const int r4 = rowptr[node0+4];
    const float d0 = dis[node0+0], d1 = dis[node0+1];
    const float d2v = dis[node0+2], d3 = dis[node0+3];

    int mx = max(max(r1-r0, r2-r1), max(r3-r2, r4-r3));
    const int nsteps = (mx + 7) >> 3;

    float a0[8], a1[8], a2[8], a3[8];
    #pragma unroll
    for (int k = 0; k < 8; ++k) { a0[k]=0.f; a1[k]=0.f; a2[k]=0.f; a3[k]=0.f; }

    // step-0 indices and edata
    int ia0 = r0 + g, ia1 = r1 + g, ia2 = r2 + g, ia3 = r3 + g;
    unsigned m0 = edata[ia0 < r1 ? ia0 : 0];
    unsigned m1 = edata[ia1 < r2 ? ia1 : 0];
    unsigned m2 = edata[ia2 < r3 ? ia2 : 0];
    unsigned m3 = edata[ia3 < r4 ? ia3 : 0];
    // step-0 h (current) + coefs
    uint4 w0 = h4[(size_t)(m0 & 0x1ffffu)*8 + l];
    uint4 w1 = h4[(size_t)(m1 & 0x1ffffu)*8 + l];
    uint4 w2 = h4[(size_t)(m2 & 0x1ffffu)*8 + l];
    uint4 w3 = h4[(size_t)(m3 & 0x1ffffu)*8 + l];
    float c0 = (ia0 < r1) ? __int_as_float((int)(m0 & 0xFFFE0000u)) * d0  : 0.f;
    float c1 = (ia1 < r2) ? __int_as_float((int)(m1 & 0xFFFE0000u)) * d1  : 0.f;
    float c2 = (ia2 < r3) ? __int_as_float((int)(m2 & 0xFFFE0000u)) * d2v : 0.f;
    float c3 = (ia3 < r4) ? __int_as_float((int)(m3 & 0xFFFE0000u)) * d3  : 0.f;
    // step-1 indices and edata (2-ahead prefetch)
    int ib0 = ia0 + 8, ib1 = ia1 + 8, ib2 = ia2 + 8, ib3 = ia3 + 8;
    unsigned n0 = edata[ib0 < r1 ? ib0 : 0];
    unsigned n1 = edata[ib1 < r2 ? ib1 : 0];
    unsigned n2 = edata[ib2 < r3 ? ib2 : 0];
    unsigned n3 = edata[ib3 < r4 ? ib3 : 0];

    for (int s = 0; s < nsteps; ++s) {
        // issue h for step s+1 (n* loaded one iteration ago — no stall)
        uint4 x0 = h4[(size_t)(n0 & 0x1ffffu)*8 + l];
        uint4 x1 = h4[(size_t)(n1 & 0x1ffffu)*8 + l];
        uint4 x2 = h4[(size_t)(n2 & 0x1ffffu)*8 + l];
        uint4 x3 = h4[(size_t)(n3 & 0x1ffffu)*8 + l];
        float e0 = (ib0 < r1) ? __int_as_float((int)(n0 & 0xFFFE0000u)) * d0  : 0.f;
        float e1 = (ib1 < r2) ? __int_as_float((int)(n1 & 0xFFFE0000u)) * d1  : 0.f;
        float e2 = (ib2 < r3) ? __int_as_float((int)(n2 & 0xFFFE0000u)) * d2v : 0.f;
        float e3 = (ib3 < r4) ? __int_as_float((int)(n3 & 0xFFFE0000u)) * d3  : 0.f;
        // issue edata for step s+2
        ib0 += 8; ib1 += 8; ib2 += 8; ib3 += 8;
        n0 = edata[ib0 < r1 ? ib0 : 0];
        n1 = edata[ib1 < r2 ? ib1 : 0];
        n2 = edata[ib2 < r3 ? ib2 : 0];
        n3 = edata[ib3 < r4 ? ib3 : 0];
        // FMA step s (w* issued one iteration ago — latency covered)
        {   const unsigned ww[4] = {w0.x, w0.y, w0.z, w0.w};
            #pragma unroll
            for (int t = 0; t < 4; ++t) {
                a0[2*t]   = fmaf(c0, blo(ww[t]), a0[2*t]);
                a0[2*t+1] = fmaf(c0, bhi(ww[t]), a0[2*t+1]);
            } }
        {   const unsigned ww[4] = {w1.x, w1.y, w1.z, w1.w};
            #pragma unroll
            for (int t = 0; t < 4; ++t) {
                a1[2*t]   = fmaf(c1, blo(ww[t]), a1[2*t]);
                a1[2*t+1] = fmaf(c1, bhi(ww[t]), a1[2*t+1]);
            } }
        {   const unsigned ww[4] = {w2.x, w2.y, w2.z, w2.w};
            #pragma unroll
            for (int t = 0; t < 4; ++t) {
                a2[2*t]   = fmaf(c2, blo(ww[t]), a2[2*t]);
                a2[2*t+1] = fmaf(c2, bhi(ww[t]), a2[2*t+1]);
            } }
        {   const unsigned ww[4] = {w3.x, w3.y, w3.z, w3.w};
            #pragma unroll
            for (int t = 0; t < 4; ++t) {
                a3[2*t]   = fmaf(c3, blo(ww[t]), a3[2*t]);
                a3[2*t+1] = fmaf(c3, bhi(ww[t]), a3[2*t+1]);
            } }
        // rotate pipeline
        w0 = x0; w1 = x1; w2 = x2; w3 = x3;
        c0 = e0; c1 = e1; c2 = e2; c3 = e3;
    }

    // reduce across the 8 edge slots (lane strides 8,16,32)
    #pragma unroll
    for (int k = 0; k < 8; ++k) {
        a0[k] += __shfl_xor(a0[k], 8);  a0[k] += __shfl_xor(a0[k], 16); a0[k] += __shfl_xor(a0[k], 32);
        a1[k] += __shfl_xor(a1[k], 8);  a1[k] += __shfl_xor(a1[k], 16); a1[k] += __shfl_xor(a1[k], 32);
        a2[k] += __shfl_xor(a2[k], 8);  a2[k] += __shfl_xor(a2[k], 16); a2[k] += __shfl_xor(a2[k], 32);
        a3[k] += __shfl_xor(a3[k], 8);  a3[k] += __shfl_xor(a3[k], 16); a3[k] += __shfl_xor(a3[k], 32);
    }

    if (g == 0) {
        float bb_[8];
        #pragma unroll
        for (int t = 0; t < 8; ++t) bb_[t] = ld1(bias, l*8 + t, f);
        {   uint4 hv = h4[(size_t)(node0+0)*8 + l];
            const unsigned hw[4] = {hv.x, hv.y, hv.z, hv.w};
            uint4 o;
            float s0 = a0[0]+bb_[0]+d0*blo(hw[0]), s1 = a0[1]+bb_[1]+d0*bhi(hw[0]);
            float s2 = a0[2]+bb_[2]+d0*blo(hw[1]), s3 = a0[3]+bb_[3]+d0*bhi(hw[1]);
            float s4 = a0[4]+bb_[4]+d0*blo(hw[2]), s5 = a0[5]+bb_[5]+d0*bhi(hw[2]);
            float s6 = a0[6]+bb_[6]+d0*blo(hw[3]), s7 = a0[7]+bb_[7]+d0*bhi(hw[3]);
            o.x = (unsigned)f2bf(s0)|((unsigned)f2bf(s1)<<16);
            o.y = (unsigned)f2bf(s2)|((unsigned)f2bf(s3)<<16);
            o.z = (unsigned)f2bf(s4)|((unsigned)f2bf(s5)<<16);
            o.w = (unsigned)f2bf(s6)|((unsigned)f2bf(s7)<<16);
            *(uint4*)&aggB[(size_t)(node0+0)*32 + l*4] = o; }
        {   uint4 hv = h4[(size_t)(node0+1)*8 + l];
            const unsigned hw[4] = {hv.x, hv.y, hv.z, hv.w};
            uint4 o;
            float s0 = a1[0]+bb_[0]+d1*blo(hw[0]), s1 = a1[1]+bb_[1]+d1*bhi(hw[0]);
            float s2 = a1[2]+bb_[2]+d1*blo(hw[1]), s3 = a1[3]+bb_[3]+d1*bhi(hw[1]);
            float s4 = a1[4]+bb_[4]+d1*blo(hw[2]), s5 = a1[5]+bb_[5]+d1*bhi(hw[2]);
            float s6 = a1[6]+bb_[6]+d1*blo(hw[3]), s7 = a1[7]+bb_[7]+d1*bhi(hw[3]);
            o.x = (unsigned)f2bf(s0)|((unsigned)f2bf(s1)<<16);
            o.y = (unsigned)f2bf(s2)|((unsigned)f2bf(s3)<<16);
            o.z = (unsigned)f2bf(s4)|((unsigned)f2bf(s5)<<16);
            o.w = (unsigned)f2bf(s6)|((unsigned)f2bf(s7)<<16);
            *(uint4*)&aggB[(size_t)(node0+1)*32 + l*4] = o; }
        {   uint4 hv = h4[(size_t)(node0+2)*8 + l];
            const unsigned hw[4] = {hv.x, hv.y, hv.z, hv.w};
            uint4 o;
            float s0 = a2[0]+bb_[0]+d2v*blo(hw[0]), s1 = a2[1]+bb_[1]+d2v*bhi(hw[0]);
            float s2 = a2[2]+bb_[2]+d2v*blo(hw[1]), s3 = a2[3]+bb_[3]+d2v*bhi(hw[1]);
            float s4 = a2[4]+bb_[4]+d2v*blo(hw[2]), s5 = a2[5]+bb_[5]+d2v*bhi(hw[2]);
            float s6 = a2[6]+bb_[6]+d2v*blo(hw[3]), s7 = a2[7]+bb_[7]+d2v*bhi(hw[3]);
            o.x = (unsigned)f2bf(s0)|((unsigned)f2bf(s1)<<16);
            o.y = (unsigned)f2bf(s2)|((unsigned)f2bf(s3)<<16);
            o.z = (unsigned)f2bf(s4)|((unsigned)f2bf(s5)<<16);
            o.w = (unsigned)f2bf(s6)|((unsigned)f2bf(s7)<<16);
            *(uint4*)&aggB[(size_t)(node0+2)*32 + l*4] = o; }
        {   uint4 hv = h4[(size_t)(node0+3)*8 + l];
            const unsigned hw[4] = {hv.x, hv.y, hv.z, hv.w};
            uint4 o;
            float s0 = a3[0]+bb_[0]+d3*blo(hw[0]), s1 = a3[1]+bb_[1]+d3*bhi(hw[0]);
            float s2 = a3[2]+bb_[2]+d3*blo(hw[1]), s3 = a3[3]+bb_[3]+d3*bhi(hw[1]);
            float s4 = a3[4]+bb_[4]+d3*blo(hw[2]), s5 = a3[5]+bb_[5]+d3*bhi(hw[2]);
            float s6 = a3[6]+bb_[6]+d3*blo(hw[3]), s7 = a3[7]+bb_[7]+d3*bhi(hw[3]);
            o.x = (unsigned)f2bf(s0)|((unsigned)f2bf(s1)<<16);
            o.y = (unsigned)f2bf(s2)|((unsigned)f2bf(s3)<<16);
            o.z = (unsigned)f2bf(s4)|((unsigned)f2bf(s5)<<16);
            o.w = (unsigned)f2bf(s6)|((unsigned)f2bf(s7)<<16);
            *(uint4*)&aggB[(size_t)(node0+3)*32 + l*4] = o; }
    }
}

// ================= dense kernels =================

__global__ __launch_bounds__(256) void k_gemm1(
    const int* __restrict__ flag, const void* __restrict__ x,
    const void* __restrict__ W, const void* __restrict__ bias,
    const float* __restrict__ dis, unsigned short* __restrict__ h_out) {
    __shared__ __align__(16) float ws[128*64];
    __shared__ __align__(16) float xs[64*64];
    const int f = flag[0];
    const int tid = threadIdx.x;
    const int rowbase = blockIdx.x * 64;
    #pragma unroll
    for (int it = 0; it < 8; ++it) {
        int g = it*256 + tid;
        float4 v = ld4(W, g, f);
        int b = g*4;
        ws[b]=v.x; ws[b+1]=v.y; ws[b+2]=v.z; ws[b+3]=v.w;
    }
    const int tr = (tid >> 4) << 2;
    const int tc = (tid & 15) << 2;
    const int row = tid & 63;
    const int grow = rowbase + row;
    const bool valid = grow < NN;
    float acc[4][4] = {};
    for (int half = 0; half < 2; ++half) {
        __syncthreads();
        #pragma unroll
        for (int it = 0; it < 4; ++it) {
            int f4 = (tid >> 6) + it*4;
            int kl = f4*4;
            float4 v = make_float4(0,0,0,0);
            if (valid) v = ld4(x, (size_t)grow*32 + half*16 + f4, f);
            xs[(kl+0)*64+row]=v.x; xs[(kl+1)*64+row]=v.y;
            xs[(kl+2)*64+row]=v.z; xs[(kl+3)*64+row]=v.w;
        }
        __syncthreads();
        #pragma unroll 8
        for (int k = 0; k < 64; ++k) {
            const float4 av = *(const float4*)&xs[k*64 + tr];
            const float4 wv = *(const float4*)&ws[(half*64 + k)*64 + tc];
            const float aa[4] = {av.x, av.y, av.z, av.w};
            const float ww[4] = {wv.x, wv.y, wv.z, wv.w};
            #pragma unroll
            for (int i = 0; i < 4; ++i)
                #pragma unroll
                for (int j = 0; j < 4; ++j)
                    acc[i][j] = fmaf(aa[i], ww[j], acc[i][j]);
        }
    }
    #pragma unroll
    for (int i = 0; i < 4; ++i) {
        int r = rowbase + tr + i;
        if (r < NN) {
            float hm = dis[r];
            ushort4 hv = make_ushort4(f2bf(acc[i][0]*hm), f2bf(acc[i][1]*hm),
                                      f2bf(acc[i][2]*hm), f2bf(acc[i][3]*hm));
            *(ushort4*)&h_out[(size_t)r*64 + tc] = hv;
        }
    }
}

// BN column stats over bf16 tensor (uint2 = 4 features); 512 blocks
__global__ __launch_bounds__(256) void k_bnstats_bf(const uint2* __restrict__ src,
                                                    float* __restrict__ sumout, int relu) {
    const int tid = threadIdx.x;
    float s0=0,s1=0,s2=0,s3=0, q0=0,q1=0,q2=0,q3=0;
    for (int g = blockIdx.x*256 + tid; g < NN*16; g += 512*256) {
        uint2 u = src[g];
        float vx = blo(u.x), vy = bhi(u.x), vz = blo(u.y), vw = bhi(u.y);
        if (relu) { vx=fmaxf(vx,0.f); vy=fmaxf(vy,0.f);
                    vz=fmaxf(vz,0.f); vw=fmaxf(vw,0.f); }
        s0+=vx; q0+=vx*vx; s1+=vy; q1+=vy*vy;
        s2+=vz; q2+=vz*vz; s3+=vw; q3+=vw*vw;
    }
    __shared__ float ls[1024], lq[1024];
    ls[tid*4+0]=s0; ls[tid*4+1]=s1; ls[tid*4+2]=s2; ls[tid*4+3]=s3;
    lq[tid*4+0]=q0; lq[tid*4+1]=q1; lq[tid*4+2]=q2; lq[tid*4+3]=q3;
    __syncthreads();
    if (tid < 64) {
        int grp = tid >> 2, k = tid & 3;
        float s = 0.f, q = 0.f;
        #pragma unroll
        for (int m = 0; m < 16; ++m) {
            int idx = (grp + 16*m)*4 + k;
            s += ls[idx]; q += lq[idx];
        }
        unsafeAtomicAdd(&sumout[tid], s);
        unsafeAtomicAdd(&sumout[64+tid], q);
    }
}

// 64x64 GEMM, bf16 input with fused BN (+relu).
template<bool RELU, bool AGG>
__global__ __launch_bounds__(256) void k_gemm64(
    const int* __restrict__ flag, const unsigned short* __restrict__ in,
    const void* __restrict__ W, const void* __restrict__ bias,
    const void* __restrict__ g, const void* __restrict__ bb,
    const float* __restrict__ insums, const float* __restrict__ dis,
    unsigned short* __restrict__ out_bf, float* __restrict__ outsums) {
    __shared__ __align__(16) float ws[64*64];
    __shared__ __align__(16) float xs[64*64];
    __shared__ float sc[64], sh[64];
    const int f = flag[0];
    const int tid = threadIdx.x;
    const int rowbase = blockIdx.x * 64;
    if (tid < 64) {
        float mean = insums[tid] * INV_N;
        float var  = fmaxf(insums[64+tid] * INV_N - mean*mean, 0.f);
        float s = ld1(g, tid, f) * rsqrtf(var + BN_EPS);
        sc[tid] = s;
        sh[tid] = ld1(bb, tid, f) - mean*s;
    }
    #pragma unroll
    for (int it = 0; it < 4; ++it) {
        int gi = it*256 + tid;
        float4 v = ld4(W, gi, f);
        int b = gi*4;
        ws[b]=v.x; ws[b+1]=v.y; ws[b+2]=v.z; ws[b+3]=v.w;
    }
    __syncthreads();
    {
        int row = tid & 63;
        int grow = rowbase + row;
        bool valid = grow < NN;
        #pragma unroll
        for (int it = 0; it < 4; ++it) {
            int f4 = (tid >> 6) + it*4;
            int k = f4*4;
            float a0=0,a1=0,a2=0,a3=0;
            if (valid) {
                ushort4 u = *(const ushort4*)&in[(size_t)grow*64 + k];
                a0=bf2f(u.x); a1=bf2f(u.y); a2=bf2f(u.z); a3=bf2f(u.w);
            }
            if (RELU) { a0=fmaxf(a0,0.f); a1=fmaxf(a1,0.f); a2=fmaxf(a2,0.f); a3=fmaxf(a3,0.f); }
            a0 = a0*sc[k+0]+sh[k+0]; a1 = a1*sc[k+1]+sh[k+1];
            a2 = a2*sc[k+2]+sh[k+2]; a3 = a3*sc[k+3]+sh[k+3];
            xs[(k+0)*64+row]=a0; xs[(k+1)*64+row]=a1;
            xs[(k+2)*64+row]=a2; xs[(k+3)*64+row]=a3;
        }
    }
    __syncthreads();
    const int tr = (tid >> 4) << 2;
    const int tc = (tid & 15) << 2;
    float acc[4][4] = {};
    #pragma unroll 8
    for (int k = 0; k < 64; ++k) {
        const float4 av = *(const float4*)&xs[k*64 + tr];
        const float4 wv = *(const float4*)&ws[k*64 + tc];
        const float aa[4] = {av.x, av.y, av.z, av.w};
        const float ww[4] = {wv.x, wv.y, wv.z, wv.w};
        #pragma unroll
        for (int i = 0; i < 4; ++i)
            #pragma unroll
            for (int j = 0; j < 4; ++j)
                acc[i][j] = fmaf(aa[i], ww[j], acc[i][j]);
    }
    float bc[4];
    #pragma unroll
    for (int j = 0; j < 4; ++j) bc[j] = ld1(bias, tc+j, f);
    if (AGG) {
        #pragma unroll
        for (int i = 0; i < 4; ++i) {
            int r = rowbase + tr + i;
            if (r < NN) {
                float hm = dis[r];
                ushort4 hv = make_ushort4(f2bf(acc[i][0]*hm), f2bf(acc[i][1]*hm),
                                          f2bf(acc[i][2]*hm), f2bf(acc[i][3]*hm));
                *(ushort4*)&out_bf[(size_t)r*64 + tc] = hv;
            }
        }
    } else {
        float ps[4] = {0,0,0,0}, pq[4] = {0,0,0,0};
        #pragma unroll
        for (int i = 0; i < 4; ++i) {
            int r = rowbase + tr + i;
            if (r < NN) {
                float y0 = acc[i][0]+bc[0], y1 = acc[i][1]+bc[1];
                float y2 = acc[i][2]+bc[2], y3 = acc[i][3]+bc[3];
                *(ushort4*)&out_bf[(size_t)r*64 + tc] =
                    make_ushort4(f2bf(y0), f2bf(y1), f2bf(y2), f2bf(y3));
                ps[0]+=y0; ps[1]+=y1; ps[2]+=y2; ps[3]+=y3;
                pq[0]+=y0*y0; pq[1]+=y1*y1; pq[2]+=y2*y2; pq[3]+=y3*y3;
            }
        }
        __syncthreads();
        int grp = tid >> 4;
        #pragma unroll
        for (int j = 0; j < 4; ++j) { xs[grp*64 + tc+j] = ps[j]; ws[grp*64 + tc+j] = pq[j]; }
        __syncthreads();
        if (tid < 64) {
            float s = 0.f, q = 0.f;
            #pragma unroll
            for (int g2 = 0; g2 < 16; ++g2) { s += xs[g2*64+tid]; q += ws[g2*64+tid]; }
            unsafeAtomicAdd(&outsums[tid], s);
            unsafeAtomicAdd(&outsums[64+tid], q);
        }
    }
}

// final: out = bn3(y3_bf16) @ lin2_W + lin2_b
__global__ __launch_bounds__(256) void k_final(
    const int* __restrict__ flag, const unsigned short* __restrict__ y3,
    const void* __restrict__ g, const void* __restrict__ bb,
    const float* __restrict__ sums, const void* __restrict__ w2,
    const void* __restrict__ b2, void* __restrict__ out) {
    __shared__ __align__(16) float tile[64*64];
    __shared__ float wp[64], tv[64];
    const int f = flag[0];
    const int tid = threadIdx.x;
    const int base = blockIdx.x * 64;
    if (tid < 64) {
        float mean = sums[tid] * INV_N;
        float var  = fmaxf(sums[64+tid] * INV_N - mean*mean, 0.f);
        float s = ld1(g, tid, f) * rsqrtf(var + BN_EPS);
        float t = ld1(bb, tid, f) - mean*s;
        float w = ld1(w2, tid, f);
        wp[tid] = s*w; tv[tid] = t*w;
    }
    #pragma unroll
    for (int it = 0; it < 4; ++it) {
        int i4 = it*256 + tid;
        int row = i4 >> 4, c4 = (i4 & 15)*4;
        float4 v = make_float4(0,0,0,0);
        if (base + row < NN) {
            ushort4 u = *(const ushort4*)&y3[(size_t)(base+row)*64 + c4];
            v = make_float4(bf2f(u.x), bf2f(u.y), bf2f(u.z), bf2f(u.w));
        }
        *(float4*)&tile[row*64 + c4] = v;
    }
    __syncthreads();
    if (tid < 64 && base + tid < NN) {
        float a = ld1(b2, 0, f);
        #pragma unroll
        for (int c = 0; c < 64; ++c) a += tv[c];
        #pragma unroll
        for (int cc = 0; cc < 64; ++cc) {
            int c = (cc + tid) & 63;
            a += tile[tid*64 + c] * wp[c];
        }
        if (f) ((float*)out)[base + tid] = a;
        else   ((unsigned short*)out)[base + tid] = f2bf(a);
    }
}

extern "C" void kernel_launch(void* const* d_in, const int* in_sizes, int n_in,
                              void* d_out, int out_size, void* d_ws, size_t ws_size,
                              hipStream_t stream) {
    const unsigned short* x = (const unsigned short*)d_in[0];
    const void* ew  = d_in[1];
    const void* W1  = d_in[2];
    const void* b1  = d_in[3];
    const void* W2  = d_in[4];
    const void* b2  = d_in[5];
    const void* l1W = d_in[6];
    const void* l1b = d_in[7];
    const void* l2W = d_in[8];
    const void* l2b = d_in[9];
    const void* g1  = d_in[10];
    const void* bb1 = d_in[11];
    const void* g2  = d_in[12];
    const void* bb2 = d_in[13];
    const void* g3  = d_in[14];
    const void* bb3 = d_in[15];
    const int* eidx = (const int*)d_in[16];

    // layout (float idx): flag 0, sums 16, dis 400;
    // region 100400..6500400: scr(int2) during preprocessing, then aggB (bf16)
    // hbuf(bf16) 6500400..9700400, histmat/rowptr 9700400, btot 10500656,
    // bstart 10502224, edata 10503792..13703792. Need 54.8 MB (proven).
    int*   flag = (int*)d_ws;
    float* wsf  = (float*)d_ws;
    float* sums = wsf + 16;
    float* dis  = wsf + 400;
    unsigned*       aggB = (unsigned*)(wsf + 100400);
    unsigned short* aggS = (unsigned short*)(wsf + 100400);
    unsigned short* hbuf = (unsigned short*)(wsf + 6500400);
    int*      histmat = (int*)(wsf + 9700400);
    int*      rowptr2 = histmat;
    int*      btot    = (int*)(wsf + 10500656);
    int*      bstart  = (int*)(wsf + 10502224);
    unsigned* edata   = (unsigned*)(wsf + 10503792);
    int2*     scr     = (int2*)(wsf + 100400);
    const size_t NEED = (size_t)13703792 * 4;
    if (ws_size < NEED) return;

    k_detect2  <<<1, 256, 0, stream>>>(x, eidx, flag, sums);
    k_hist     <<<NSB, 256, 0, stream>>>(flag, eidx, histmat);
    k_scanA    <<<NBK, 256, 0, stream>>>(histmat, btot);
    k_scanB    <<<1, 1024, 0, stream>>>(btot, bstart);
    k_scatter  <<<NSB, 256, 0, stream>>>(flag, eidx, ew, histmat, bstart, scr);
    k_sortdeg  <<<NBK, 256, 0, stream>>>(bstart, scr, edata, rowptr2, dis);
    // layer 1
    k_gemm1    <<<1563, 256, 0, stream>>>(flag, x, W1, b1, dis, hbuf);
    k_gather7  <<<NN/16, 256, 0, stream>>>(flag, rowptr2, edata, dis, b1,
                                           (const unsigned*)hbuf, aggB);
    k_bnstats_bf<<<512, 256, 0, stream>>>((const uint2*)aggB, sums + 0, 1);
    // layer 2
    k_gemm64<true, true><<<1563, 256, 0, stream>>>(flag, aggS, W2, b2, g1, bb1,
                                                   sums + 0, dis, hbuf, nullptr);
    k_gather7  <<<NN/16, 256, 0, stream>>>(flag, rowptr2, edata, dis, b2,
                                           (const unsigned*)hbuf, aggB);
    k_bnstats_bf<<<512, 256, 0, stream>>>((const uint2*)aggB, sums + 128, 0);
    // lin1 (+ bn3 stats), y3 bf16 in place over agg2
    k_gemm64<false, false><<<1563, 256, 0, stream>>>(flag, aggS, l1W, l1b, g2, bb2,
                                                     sums + 128, dis, aggS, sums + 256);
    k_final    <<<1563, 256, 0, stream>>>(flag, aggS, g3, bb3, sums + 256, l2W, l2b, d_out);
}

// Round 7
// 598.517 us; speedup vs baseline: 1.6831x; 1.0059x over previous
//
#include <hip/hip_runtime.h>
#include <hip/hip_bf16.h>

// R23 = R22 resubmit (infra failure, kernel never ran — same as R1/R17).
// Quarter-split + pipelined gather (k_gather8) — combines R17's L2
// residency with R21's deep pipeline. Evidence chain:
//  - full-table random gather pinned at ~3.3 TB/s L2-miss service (gather3/
//    5/7 all 94-99us at 38-80% occupancy -> parallelism-insensitive wall)
//  - quarter-split (gather4) cut FETCH 297->117MB but was L2-hit-latency
//    bound (shallow 2-load structure) + 4x per-node overhead -> 148us
//  - gather7 skeleton: 4-node-concurrent, 2-deep pipeline, spill-free
// gather8: h stored QUARTER-MAJOR (h[q][node][8 uints]); one dispatch,
// blockIdx-major quarters (all XCDs work one quarter at a time -> 3.2MB
// table L2-resident). Wave = 8 edge-slots x 8 lanes; lane loads 4B (2
// feats) of the 32B quarter row; 4 nodes concurrent; edata prefetched 2
// steps, h 1 step ahead; 8 loads in flight; pipeline state ~50 VGPR so the
// compiler can keep it (gather7's uint4 state got serialized at VGPR=52).
// launch_bounds(256,6): cap 85 VGPR — forced-spill insurance (R20 lesson).
// Rest identical to R16: zero-global-atomic counting sort, w15-packed edata,
// h bf16 pre-scaled by dis[src], bf16 intermediates, BN/relu fused in GEMMs.

#define NN 100000
#define NE 3200000
#define INV_N (1.0f/100000.0f)
#define BN_EPS 1e-5f
#define NBK 782            // buckets of 128 nodes
#define NSB 512            // scatter/hist blocks
#define EPB 6250           // edges per scatter/hist block (NSB*EPB == NE)
#define CAPB 6144          // LDS staging per bucket (mean 4092 + 32 sigma)
#define QBLK8 6250         // gather blocks per quarter (4 waves x 4 nodes)

static __device__ __forceinline__ float bf2f(unsigned short u) {
    if ((u & 0x7f80u) == 0x7f80u) u = 0;          // inf/NaN -> 0 (input scrub)
    union { unsigned int i; float f; } z; z.i = ((unsigned int)u) << 16; return z.f;
}
static __device__ __forceinline__ float scrubf(float v) {
    return (fabsf(v) < 1e30f) ? v : 0.f;
}
static __device__ __forceinline__ unsigned short f2bf(float v) {
    union { float f; unsigned int i; } z; z.f = v;
    unsigned int lsb = (z.i >> 16) & 1u; z.i += 0x7fffu + lsb;
    return (unsigned short)(z.i >> 16);
}
static __device__ __forceinline__ float ld1(const void* p, size_t i, int f) {
    return f ? scrubf(((const float*)p)[i]) : bf2f(((const unsigned short*)p)[i]);
}
static __device__ __forceinline__ float4 ld4(const void* p, size_t g, int f) {
    if (f) { float4 v = ((const float4*)p)[g];
             return make_float4(scrubf(v.x),scrubf(v.y),scrubf(v.z),scrubf(v.w)); }
    ushort4 u = ((const ushort4*)p)[g];
    return make_float4(bf2f(u.x),bf2f(u.y),bf2f(u.z),bf2f(u.w));
}
static __device__ __forceinline__ int getidx(const int* ei, size_t pos, int i64) {
    return i64 ? ei[2*pos] : ei[pos];
}
static __device__ __forceinline__ float blo(unsigned v) {
    union { unsigned u; float f; } z; z.u = v << 16; return z.f;
}
static __device__ __forceinline__ float bhi(unsigned v) {
    union { unsigned u; float f; } z; z.u = v & 0xffff0000u; return z.f;
}
static __device__ __forceinline__ unsigned w15of(unsigned wu) {
    unsigned lsb = (wu >> 17) & 1u;
    return ((wu + 0xFFFFu + lsb) >> 17) & 0x7fffu;
}

// ---------------- detector + sums zero ----------------
__global__ void k_detect2(const unsigned short* __restrict__ x,
                          const int* __restrict__ ei, int* __restrict__ flag,
                          float* __restrict__ sums) {
    __shared__ int cnt[256];
    int tid = threadIdx.x, c = 0;
    for (int i = tid; i < 1024; i += 256) {
        unsigned short u = x[i];
        int ex = (u >> 7) & 0xff;
        if ((u & 0x7fffu) != 0 && (ex >= 0xB0 || ex <= 0x40)) c++;
    }
    cnt[tid] = c; __syncthreads();
    if (tid == 0) { int t = 0; for (int i = 0; i < 256; ++i) t += cnt[i];
                    flag[0] = (t > 64) ? 1 : 0; }
    if (tid == 1) { int nz = 0; for (int i = 1; i < 64; i += 2) nz |= ei[i];
                    flag[1] = (nz == 0) ? 1 : 0; }
    if (tid < 128) { sums[tid]=0.f; sums[128+tid]=0.f; sums[256+tid]=0.f; }
}

// ================= bucket counting sort (no global atomics) =================

__global__ __launch_bounds__(256) void k_hist(const int* __restrict__ flag,
                                              const int* __restrict__ ei,
                                              int* __restrict__ histmat) {
    __shared__ int hh[NBK];
    const int i64 = flag[1];
    const int blk = blockIdx.x, tid = threadIdx.x;
    for (int b = tid; b < NBK; b += 256) hh[b] = 0;
    __syncthreads();
    const size_t e0 = (size_t)blk * EPB;
    for (int e = tid; e < EPB; e += 256) {
        unsigned d = (unsigned)getidx(ei, NE + e0 + e, i64);
        if (d < NN) atomicAdd(&hh[d >> 7], 1);
    }
    __syncthreads();
    for (int b = tid; b < NBK; b += 256) histmat[blk*NBK + b] = hh[b];
}

// per-bucket column scan across the NSB=512 blocks (exclusive), total -> btot
__global__ __launch_bounds__(256) void k_scanA(int* __restrict__ histmat,
                                               int* __restrict__ btot) {
    __shared__ int sd[256];
    const int b = blockIdx.x, t = threadIdx.x;
    int v0 = histmat[(2*t)*NBK + b];
    int v1 = histmat[(2*t+1)*NBK + b];
    int ts = v0 + v1;
    sd[t] = ts; __syncthreads();
    #pragma unroll
    for (int ofs = 1; ofs < 256; ofs <<= 1) {
        int a = (t >= ofs) ? sd[t-ofs] : 0;
        __syncthreads(); sd[t] += a; __syncthreads();
    }
    int excl = sd[t] - ts;
    histmat[(2*t)*NBK + b]   = excl;
    histmat[(2*t+1)*NBK + b] = excl + v0;
    if (t == 255) btot[b] = sd[255];
}

__global__ void k_scanB(const int* __restrict__ btot, int* __restrict__ bstart) {
    __shared__ int sd[1024];
    int t = threadIdx.x;                 // 1024 threads; NBK=782 < 1024
    int v = (t < NBK) ? btot[t] : 0;
    sd[t] = v; __syncthreads();
    #pragma unroll
    for (int ofs = 1; ofs < 1024; ofs <<= 1) {
        int a = (t >= ofs) ? sd[t-ofs] : 0;
        __syncthreads(); sd[t] += a; __syncthreads();
    }
    if (t <= NBK) bstart[t] = sd[t] - v;   // exclusive; bstart[NBK] = total
}

__global__ __launch_bounds__(256) void k_scatter(
    const int* __restrict__ flag, const int* __restrict__ ei,
    const void* __restrict__ ew, const int* __restrict__ histmat,
    const int* __restrict__ bstart, int2* __restrict__ scr) {
    __shared__ int cursor[NBK];
    const int f = flag[0], i64 = flag[1];
    const int blk = blockIdx.x, tid = threadIdx.x;
    for (int b = tid; b < NBK; b += 256)
        cursor[b] = histmat[blk*NBK + b] + bstart[b];
    __syncthreads();
    const size_t e0 = (size_t)blk * EPB;
    for (int e = tid; e < EPB; e += 256) {
        unsigned d = (unsigned)getidx(ei, NE + e0 + e, i64);
        if (d >= NN) continue;
        unsigned s = (unsigned)getidx(ei, e0 + e, i64);
        float w = ld1(ew, e0 + e, f);
        if (s >= NN) { s = 0; w = 0.f; }
        int pos = atomicAdd(&cursor[d >> 7], 1);
        scr[pos] = make_int2((int)(((d & 127u) << 17) | s), __float_as_int(w));
    }
}

// fused node-sort + degree over 128-node buckets; w15 staged in LDS;
// coalesced edata write. Overflow (> CAPB, never here): scattered-write path.
__global__ __launch_bounds__(256) void k_sortdeg(
    const int* __restrict__ bstart, const int2* __restrict__ scr,
    unsigned* __restrict__ edata, int* __restrict__ rowptr, float* __restrict__ dis) {
    __shared__ unsigned sp[CAPB];
    __shared__ unsigned out[CAPB];
    __shared__ unsigned short sww[CAPB];
    __shared__ int cnt[128], scn[128], cur[128];
    __shared__ float degf[128];
    const int b = blockIdx.x, tid = threadIdx.x;
    const int node0 = b * 128;
    const int r0 = bstart[b], r1 = bstart[b+1], n = r1 - r0;
    const bool fit = (n <= CAPB);

    if (tid < 128) { cnt[tid] = 0; degf[tid] = 1.0f; }
    __syncthreads();
    if (fit) {
        for (int j = tid; j < n; j += 256) {
            int2 m = scr[r0 + j];
            sp[j] = (unsigned)m.x;
            sww[j] = (unsigned short)w15of((unsigned)m.y);
            int l = (m.x >> 17) & 127;
            atomicAdd(&cnt[l], 1);
            atomicAdd(&degf[l], __int_as_float(m.y));
        }
    } else {
        for (int j = tid; j < n; j += 256) {
            int2 m = scr[r0 + j];
            int l = (m.x >> 17) & 127;
            atomicAdd(&cnt[l], 1);
            atomicAdd(&degf[l], __int_as_float(m.y));
        }
    }
    __syncthreads();
    if (tid < 128) scn[tid] = cnt[tid];
    __syncthreads();
    #pragma unroll
    for (int ofs = 1; ofs < 128; ofs <<= 1) {
        int a = 0;
        if (tid < 128 && tid >= ofs) a = scn[tid - ofs];
        __syncthreads();
        if (tid < 128) scn[tid] += a;
        __syncthreads();
    }
    if (tid < 128) {
        int excl = scn[tid] - cnt[tid];
        cur[tid] = excl;
        int node = node0 + tid;
        if (node <= NN) rowptr[node] = r0 + excl;
        if (node <  NN) dis[node] = rsqrtf(fmaxf(degf[tid], 1e-12f));
    }
    __syncthreads();
    if (fit) {
        for (int j = tid; j < n; j += 256) {
            unsigned p = sp[j];
            int l = (p >> 17) & 127;
            int pos = atomicAdd(&cur[l], 1);
            out[pos] = (p & 0x1ffffu) | ((unsigned)sww[j] << 17);
        }
        __syncthreads();
        for (int j = tid; j < n; j += 256)           // coalesced linear write
            edata[r0 + j] = out[j];
    } else {
        for (int j = tid; j < n; j += 256) {
            int2 m = scr[r0 + j];
            int l = (m.x >> 17) & 127;
            int pos = atomicAdd(&cur[l], 1);
            edata[r0 + pos] = ((unsigned)m.x & 0x1ffffu) | (w15of((unsigned)m.y) << 17);
        }
    }
}

// gather: quarter q = blockIdx/QBLK8 (blockIdx-major -> 3.2MB table
// L2-resident while its blocks run). Wave = 8 edge-slots (g) x 8 lanes (l);
// lane loads 4B (feats q*16+2l, +1) of the quarter row; 4 nodes concurrent;
// 2-deep pipeline (edata 2 ahead, h 1 ahead) = 8 loads in flight. Tail lanes
// clamp to edata[0] (coef masked 0). Epilogue: slot-reduce + self + bias;
// slot-0 lanes write 8x4B = the node's quarter of aggB (row-major).
__global__ __launch_bounds__(256, 6) void k_gather8(
    const int* __restrict__ flag, const int* __restrict__ rowptr,
    const unsigned* __restrict__ edata, const float* __restrict__ dis,
    const void* __restrict__ bias, const unsigned* __restrict__ hq,
    unsigned* __restrict__ aggB) {
    const int f = flag[0];
    const int q  = blockIdx.x / QBLK8;                     // 0..3, major order
    const int bq = blockIdx.x % QBLK8;
    const int node0 = bq * 16 + (threadIdx.x >> 6) * 4;
    const int lane = threadIdx.x & 63;
    const int g = lane >> 3;                               // edge slot 0..7
    const int l = lane & 7;                                // uint within quarter
    const unsigned* __restrict__ hb = hq + (size_t)q * (NN*8);

    const int r0 = rowptr[node0+0], r1 = rowptr[node0+1];
    const int r2 = rowptr[node0+2], r3 = rowptr[node0+3];
    const int r4 = rowptr[node0+4];
    const float d0 = dis[node0+0], d1 = dis[node0+1];
    const float d2v = dis[node0+2], d3 = dis[node0+3];

    int mx = max(max(r1-r0, r2-r1), max(r3-r2, r4-r3));
    const int nsteps = (mx + 7) >> 3;

    float a00=0.f,a01=0.f, a10=0.f,a11=0.f;
    float a20=0.f,a21=0.f, a30=0.f,a31=0.f;

    // step-0 edata + h, step-1 edata (2-ahead)
    int ia0 = r0 + g, ia1 = r1 + g, ia2 = r2 + g, ia3 = r3 + g;
    unsigned m0 = edata[ia0 < r1 ? ia0 : 0];
    unsigned m1 = edata[ia1 < r2 ? ia1 : 0];
    unsigned m2 = edata[ia2 < r3 ? ia2 : 0];
    unsigned m3 = edata[ia3 < r4 ? ia3 : 0];
    unsigned w0 = hb[(size_t)(m0 & 0x1ffffu)*8 + l];
    unsigned w1 = hb[(size_t)(m1 & 0x1ffffu)*8 + l];
    unsigned w2 = hb[(size_t)(m2 & 0x1ffffu)*8 + l];
    unsigned w3 = hb[(size_t)(m3 & 0x1ffffu)*8 + l];
    float c0 = (ia0 < r1) ? __int_as_float((int)(m0 & 0xFFFE0000u)) * d0  : 0.f;
    float c1 = (ia1 < r2) ? __int_as_float((int)(m1 & 0xFFFE0000u)) * d1  : 0.f;
    float c2 = (ia2 < r3) ? __int_as_float((int)(m2 & 0xFFFE0000u)) * d2v : 0.f;
    float c3 = (ia3 < r4) ? __int_as_float((int)(m3 & 0xFFFE0000u)) * d3  : 0.f;
    int ib0 = ia0 + 8, ib1 = ia1 + 8, ib2 = ia2 + 8, ib3 = ia3 + 8;
    unsigned n0 = edata[ib0 < r1 ? ib0 : 0];
    unsigned n1 = edata[ib1 < r2 ? ib1 : 0];
    unsigned n2 = edata[ib2 < r3 ? ib2 : 0];
    unsigned n3 = edata[ib3 < r4 ? ib3 : 0];

    for (int s = 0; s < nsteps; ++s) {
        // h for step s+1 (n* loaded one iteration ago)
        unsigned x0 = hb[(size_t)(n0 & 0x1ffffu)*8 + l];
        unsigned x1 = hb[(size_t)(n1 & 0x1ffffu)*8 + l];
        unsigned x2 = hb[(size_t)(n2 & 0x1ffffu)*8 + l];
        unsigned x3 = hb[(size_t)(n3 & 0x1ffffu)*8 + l];
        float e0 = (ib0 < r1) ? __int_as_float((int)(n0 & 0xFFFE0000u)) * d0  : 0.f;
        float e1 = (ib1 < r2) ? __int_as_float((int)(n1 & 0xFFFE0000u)) * d1  : 0.f;
        float e2 = (ib2 < r3) ? __int_as_float((int)(n2 & 0xFFFE0000u)) * d2v : 0.f;
        float e3 = (ib3 < r4) ? __int_as_float((int)(n3 & 0xFFFE0000u)) * d3  : 0.f;
        // edata for step s+2
        ib0 += 8; ib1 += 8; ib2 += 8; ib3 += 8;
        n0 = edata[ib0 < r1 ? ib0 : 0];
        n1 = edata[ib1 < r2 ? ib1 : 0];
        n2 = edata[ib2 < r3 ? ib2 : 0];
        n3 = edata[ib3 < r4 ? ib3 : 0];
        // FMA step s (w*/c* issued one iteration ago)
        a00 = fmaf(c0, blo(w0), a00); a01 = fmaf(c0, bhi(w0), a01);
        a10 = fmaf(c1, blo(w1), a10); a11 = fmaf(c1, bhi(w1), a11);
        a20 = fmaf(c2, blo(w2), a20); a21 = fmaf(c2, bhi(w2), a21);
        a30 = fmaf(c3, blo(w3), a30); a31 = fmaf(c3, bhi(w3), a31);
        // rotate pipeline
        w0 = x0; w1 = x1; w2 = x2; w3 = x3;
        c0 = e0; c1 = e1; c2 = e2; c3 = e3;
    }

    // reduce across the 8 edge slots (lane strides 8,16,32)
    a00 += __shfl_xor(a00, 8); a00 += __shfl_xor(a00, 16); a00 += __shfl_xor(a00, 32);
    a01 += __shfl_xor(a01, 8); a01 += __shfl_xor(a01, 16); a01 += __shfl_xor(a01, 32);
    a10 += __shfl_xor(a10, 8); a10 += __shfl_xor(a10, 16); a10 += __shfl_xor(a10, 32);
    a11 += __shfl_xor(a11, 8); a11 += __shfl_xor(a11, 16); a11 += __shfl_xor(a11, 32);
    a20 += __shfl_xor(a20, 8); a20 += __shfl_xor(a20, 16); a20 += __shfl_xor(a20, 32);
    a21 += __shfl_xor(a21, 8); a21 += __shfl_xor(a21, 16); a21 += __shfl_xor(a21, 32);
    a30 += __shfl_xor(a30, 8); a30 += __shfl_xor(a30, 16); a30 += __shfl_xor(a30, 32);
    a31 += __shfl_xor(a31, 8); a31 += __shfl_xor(a31, 16); a31 += __shfl_xor(a31, 32);

    if (g == 0) {
        const float b0 = ld1(bias, q*16 + 2*l,     f);
        const float b1 = ld1(bias, q*16 + 2*l + 1, f);
        unsigned h0 = hb[(size_t)(node0+0)*8 + l];
        unsigned h1 = hb[(size_t)(node0+1)*8 + l];
        unsigned h2 = hb[(size_t)(node0+2)*8 + l];
        unsigned h3 = hb[(size_t)(node0+3)*8 + l];
        aggB[(size_t)(node0+0)*32 + q*8 + l] =
            (unsigned)f2bf(a00 + b0 + d0*blo(h0)) |
            ((unsigned)f2bf(a01 + b1 + d0*bhi(h0)) << 16);
        aggB[(size_t)(node0+1)*32 + q*8 + l] =
            (unsigned)f2bf(a10 + b0 + d1*blo(h1)) |
            ((unsigned)f2bf(a11 + b1 + d1*bhi(h1)) << 16);
        aggB[(size_t)(node0+2)*32 + q*8 + l] =
            (unsigned)f2bf(a20 + b0 + d2v*blo(h2)) |
            ((unsigned)f2bf(a21 + b1 + d2v*bhi(h2)) << 16);
        aggB[(size_t)(node0+3)*32 + q*8 + l] =
            (unsigned)f2bf(a30 + b0 + d3*blo(h3)) |
            ((unsigned)f2bf(a31 + b1 + d3*bhi(h3)) << 16);
    }
}

// ================= dense kernels =================

// h_out written QUARTER-MAJOR: uint2 at h[(q*NN + r)*8 + (tc&15)/2]
__global__ __launch_bounds__(256) void k_gemm1(
    const int* __restrict__ flag, const void* __restrict__ x,
    const void* __restrict__ W, const void* __restrict__ bias,
    const float* __restrict__ dis, unsigned short* __restrict__ h_out) {
    __shared__ __align__(16) float ws[128*64];
    __shared__ __align__(16) float xs[64*64];
    const int f = flag[0];
    const int tid = threadIdx.x;
    const int rowbase = blockIdx.x * 64;
    #pragma unroll
    for (int it = 0; it < 8; ++it) {
        int g = it*256 + tid;
        float4 v = ld4(W, g, f);
        int b = g*4;
        ws[b]=v.x; ws[b+1]=v.y; ws[b+2]=v.z; ws[b+3]=v.w;
    }
    const int tr = (tid >> 4) << 2;
    const int tc = (tid & 15) << 2;
    const int row = tid & 63;
    const int grow = rowbase + row;
    const bool valid = grow < NN;
    float acc[4][4] = {};
    for (int half = 0; half < 2; ++half) {
        __syncthreads();
        #pragma unroll
        for (int it = 0; it < 4; ++it) {
            int f4 = (tid >> 6) + it*4;
            int kl = f4*4;
            float4 v = make_float4(0,0,0,0);
            if (valid) v = ld4(x, (size_t)grow*32 + half*16 + f4, f);
            xs[(kl+0)*64+row]=v.x; xs[(kl+1)*64+row]=v.y;
            xs[(kl+2)*64+row]=v.z; xs[(kl+3)*64+row]=v.w;
        }
        __syncthreads();
        #pragma unroll 8
        for (int k = 0; k < 64; ++k) {
            const float4 av = *(const float4*)&xs[k*64 + tr];
            const float4 wv = *(const float4*)&ws[(half*64 + k)*64 + tc];
            const float aa[4] = {av.x, av.y, av.z, av.w};
            const float ww[4] = {wv.x, wv.y, wv.z, wv.w};
            #pragma unroll
            for (int i = 0; i < 4; ++i)
                #pragma unroll
                for (int j = 0; j < 4; ++j)
                    acc[i][j] = fmaf(aa[i], ww[j], acc[i][j]);
        }
    }
    unsigned* __restrict__ ho = (unsigned*)h_out;
    const int qq = tc >> 4, uu = (tc & 15) >> 1;
    #pragma unroll
    for (int i = 0; i < 4; ++i) {
        int r = rowbase + tr + i;
        if (r < NN) {
            float hm = dis[r];
            unsigned p0 = (unsigned)f2bf(acc[i][0]*hm) | ((unsigned)f2bf(acc[i][1]*hm) << 16);
            unsigned p1 = (unsigned)f2bf(acc[i][2]*hm) | ((unsigned)f2bf(acc[i][3]*hm) << 16);
            *(uint2*)&ho[((size_t)qq*NN + r)*8 + uu] = make_uint2(p0, p1);
        }
    }
}

// BN column stats over bf16 tensor (uint2 = 4 features); 512 blocks
__global__ __launch_bounds__(256) void k_bnstats_bf(const uint2* __restrict__ src,
                                                    float* __restrict__ sumout, int relu) {
    const int tid = threadIdx.x;
    float s0=0,s1=0,s2=0,s3=0, q0=0,q1=0,q2=0,q3=0;
    for (int g = blockIdx.x*256 + tid; g < NN*16; g += 512*256) {
        uint2 u = src[g];
        float vx = blo(u.x), vy = bhi(u.x), vz = blo(u.y), vw = bhi(u.y);
        if (relu) { vx=fmaxf(vx,0.f); vy=fmaxf(vy,0.f);
                    vz=fmaxf(vz,0.f); vw=fmaxf(vw,0.f); }
        s0+=vx; q0+=vx*vx; s1+=vy; q1+=vy*vy;
        s2+=vz; q2+=vz*vz; s3+=vw; q3+=vw*vw;
    }
    __shared__ float ls[1024], lq[1024];
    ls[tid*4+0]=s0; ls[tid*4+1]=s1; ls[tid*4+2]=s2; ls[tid*4+3]=s3;
    lq[tid*4+0]=q0; lq[tid*4+1]=q1; lq[tid*4+2]=q2; lq[tid*4+3]=q3;
    __syncthreads();
    if (tid < 64) {
        int grp = tid >> 2, k = tid & 3;
        float s = 0.f, q = 0.f;
        #pragma unroll
        for (int m = 0; m < 16; ++m) {
            int idx = (grp + 16*m)*4 + k;
            s += ls[idx]; q += lq[idx];
        }
        unsafeAtomicAdd(&sumout[tid], s);
        unsafeAtomicAdd(&sumout[64+tid], q);
    }
}

// 64x64 GEMM, bf16 input (row-major) with fused BN (+relu).
// AGG=true: output quarter-major (feeds k_gather8); else row-major + stats.
template<bool RELU, bool AGG>
__global__ __launch_bounds__(256) void k_gemm64(
    const int* __restrict__ flag, const unsigned short* __restrict__ in,
    const void* __restrict__ W, const void* __restrict__ bias,
    const void* __restrict__ g, const void* __restrict__ bb,
    const float* __restrict__ insums, const float* __restrict__ dis,
    unsigned short* __restrict__ out_bf, float* __restrict__ outsums) {
    __shared__ __align__(16) float ws[64*64];
    __shared__ __align__(16) float xs[64*64];
    __shared__ float sc[64], sh[64];
    const int f = flag[0];
    const int tid = threadIdx.x;
    const int rowbase = blockIdx.x * 64;
    if (tid < 64) {
        float mean = insums[tid] * INV_N;
        float var  = fmaxf(insums[64+tid] * INV_N - mean*mean, 0.f);
        float s = ld1(g, tid, f) * rsqrtf(var + BN_EPS);
        sc[tid] = s;
        sh[tid] = ld1(bb, tid, f) - mean*s;
    }
    #pragma unroll
    for (int it = 0; it < 4; ++it) {
        int gi = it*256 + tid;
        float4 v = ld4(W, gi, f);
        int b = gi*4;
        ws[b]=v.x; ws[b+1]=v.y; ws[b+2]=v.z; ws[b+3]=v.w;
    }
    __syncthreads();
    {
        int row = tid & 63;
        int grow = rowbase + row;
        bool valid = grow < NN;
        #pragma unroll
        for (int it = 0; it < 4; ++it) {
            int f4 = (tid >> 6) + it*4;
            int k = f4*4;
            float a0=0,a1=0,a2=0,a3=0;
            if (valid) {
                ushort4 u = *(const ushort4*)&in[(size_t)grow*64 + k];
                a0=bf2f(u.x); a1=bf2f(u.y); a2=bf2f(u.z); a3=bf2f(u.w);
            }
            if (RELU) { a0=fmaxf(a0,0.f); a1=fmaxf(a1,0.f); a2=fmaxf(a2,0.f); a3=fmaxf(a3,0.f); }
            a0 = a0*sc[k+0]+sh[k+0]; a1 = a1*sc[k+1]+sh[k+1];
            a2 = a2*sc[k+2]+sh[k+2]; a3 = a3*sc[k+3]+sh[k+3];
            xs[(k+0)*64+row]=a0; xs[(k+1)*64+row]=a1;
            xs[(k+2)*64+row]=a2; xs[(k+3)*64+row]=a3;
        }
    }
    __syncthreads();
    const int tr = (tid >> 4) << 2;
    const int tc = (tid & 15) << 2;
    float acc[4][4] = {};
    #pragma unroll 8
    for (int k = 0; k < 64; ++k) {
        const float4 av = *(const float4*)&xs[k*64 + tr];
        const float4 wv = *(const float4*)&ws[k*64 + tc];
        const float aa[4] = {av.x, av.y, av.z, av.w};
        const float ww[4] = {wv.x, wv.y, wv.z, wv.w};
        #pragma unroll
        for (int i = 0; i < 4; ++i)
            #pragma unroll
            for (int j = 0; j < 4; ++j)
                acc[i][j] = fmaf(aa[i], ww[j], acc[i][j]);
    }
    float bc[4];
    #pragma unroll
    for (int j = 0; j < 4; ++j) bc[j] = ld1(bias, tc+j, f);
    if (AGG) {
        unsigned* __restrict__ ho = (unsigned*)out_bf;
        const int qq = tc >> 4, uu = (tc & 15) >> 1;
        #pragma unroll
        for (int i = 0; i < 4; ++i) {
            int r = rowbase + tr + i;
            if (r < NN) {
                float hm = dis[r];
                unsigned p0 = (unsigned)f2bf(acc[i][0]*hm) | ((unsigned)f2bf(acc[i][1]*hm) << 16);
                unsigned p1 = (unsigned)f2bf(acc[i][2]*hm) | ((unsigned)f2bf(acc[i][3]*hm) << 16);
                *(uint2*)&ho[((size_t)qq*NN + r)*8 + uu] = make_uint2(p0, p1);
            }
        }
    } else {
        float ps[4] = {0,0,0,0}, pq[4] = {0,0,0,0};
        #pragma unroll
        for (int i = 0; i < 4; ++i) {
            int r = rowbase + tr + i;
            if (r < NN) {
                float y0 = acc[i][0]+bc[0], y1 = acc[i][1]+bc[1];
                float y2 = acc[i][2]+bc[2], y3 = acc[i][3]+bc[3];
                *(ushort4*)&out_bf[(size_t)r*64 + tc] =
                    make_ushort4(f2bf(y0), f2bf(y1), f2bf(y2), f2bf(y3));
                ps[0]+=y0; ps[1]+=y1; ps[2]+=y2; ps[3]+=y3;
                pq[0]+=y0*y0; pq[1]+=y1*y1; pq[2]+=y2*y2; pq[3]+=y3*y3;
            }
        }
        __syncthreads();
        int grp = tid >> 4;
        #pragma unroll
        for (int j = 0; j < 4; ++j) { xs[grp*64 + tc+j] = ps[j]; ws[grp*64 + tc+j] = pq[j]; }
        __syncthreads();
        if (tid < 64) {
            float s = 0.f, q = 0.f;
            #pragma unroll
            for (int g2 = 0; g2 < 16; ++g2) { s += xs[g2*64+tid]; q += ws[g2*64+tid]; }
            unsafeAtomicAdd(&outsums[tid], s);
            unsafeAtomicAdd(&outsums[64+tid], q);
        }
    }
}

// final: out = bn3(y3_bf16) @ lin2_W + lin2_b
__global__ __launch_bounds__(256) void k_final(
    const int* __restrict__ flag, const unsigned short* __restrict__ y3,
    const void* __restrict__ g, const void* __restrict__ bb,
    const float* __restrict__ sums, const void* __restrict__ w2,
    const void* __restrict__ b2, void* __restrict__ out) {
    __shared__ __align__(16) float tile[64*64];
    __shared__ float wp[64], tv[64];
    const int f = flag[0];
    const int tid = threadIdx.x;
    const int base = blockIdx.x * 64;
    if (tid < 64) {
        float mean = sums[tid] * INV_N;
        float var  = fmaxf(sums[64+tid] * INV_N - mean*mean, 0.f);
        float s = ld1(g, tid, f) * rsqrtf(var + BN_EPS);
        float t = ld1(bb, tid, f) - mean*s;
        float w = ld1(w2, tid, f);
        wp[tid] = s*w; tv[tid] = t*w;
    }
    #pragma unroll
    for (int it = 0; it < 4; ++it) {
        int i4 = it*256 + tid;
        int row = i4 >> 4, c4 = (i4 & 15)*4;
        float4 v = make_float4(0,0,0,0);
        if (base + row < NN) {
            ushort4 u = *(const ushort4*)&y3[(size_t)(base+row)*64 + c4];
            v = make_float4(bf2f(u.x), bf2f(u.y), bf2f(u.z), bf2f(u.w));
        }
        *(float4*)&tile[row*64 + c4] = v;
    }
    __syncthreads();
    if (tid < 64 && base + tid < NN) {
        float a = ld1(b2, 0, f);
        #pragma unroll
        for (int c = 0; c < 64; ++c) a += tv[c];
        #pragma unroll
        for (int cc = 0; cc < 64; ++cc) {
            int c = (cc + tid) & 63;
            a += tile[tid*64 + c] * wp[c];
        }
        if (f) ((float*)out)[base + tid] = a;
        else   ((unsigned short*)out)[base + tid] = f2bf(a);
    }
}

extern "C" void kernel_launch(void* const* d_in, const int* in_sizes, int n_in,
                              void* d_out, int out_size, void* d_ws, size_t ws_size,
                              hipStream_t stream) {
    const unsigned short* x = (const unsigned short*)d_in[0];
    const void* ew  = d_in[1];
    const void* W1  = d_in[2];
    const void* b1  = d_in[3];
    const void* W2  = d_in[4];
    const void* b2  = d_in[5];
    const void* l1W = d_in[6];
    const void* l1b = d_in[7];
    const void* l2W = d_in[8];
    const void* l2b = d_in[9];
    const void* g1  = d_in[10];
    const void* bb1 = d_in[11];
    const void* g2  = d_in[12];
    const void* bb2 = d_in[13];
    const void* g3  = d_in[14];
    const void* bb3 = d_in[15];
    const int* eidx = (const int*)d_in[16];

    // layout (float idx): flag 0, sums 16, dis 400;
    // region 100400..6500400: scr(int2) during preprocessing, then aggB (bf16)
    // hbuf(bf16, quarter-major) 6500400..9700400, histmat/rowptr 9700400,
    // btot 10500656, bstart 10502224, edata 10503792..13703792.
    int*   flag = (int*)d_ws;
    float* wsf  = (float*)d_ws;
    float* sums = wsf + 16;
    float* dis  = wsf + 400;
    unsigned*       aggB = (unsigned*)(wsf + 100400);
    unsigned short* aggS = (unsigned short*)(wsf + 100400);
    unsigned short* hbuf = (unsigned short*)(wsf + 6500400);
    int*      histmat = (int*)(wsf + 9700400);
    int*      rowptr2 = histmat;
    int*      btot    = (int*)(wsf + 10500656);
    int*      bstart  = (int*)(wsf + 10502224);
    unsigned* edata   = (unsigned*)(wsf + 10503792);
    int2*     scr     = (int2*)(wsf + 100400);
    const size_t NEED = (size_t)13703792 * 4;
    if (ws_size < NEED) return;

    k_detect2  <<<1, 256, 0, stream>>>(x, eidx, flag, sums);
    k_hist     <<<NSB, 256, 0, stream>>>(flag, eidx, histmat);
    k_scanA    <<<NBK, 256, 0, stream>>>(histmat, btot);
    k_scanB    <<<1, 1024, 0, stream>>>(btot, bstart);
    k_scatter  <<<NSB, 256, 0, stream>>>(flag, eidx, ew, histmat, bstart, scr);
    k_sortdeg  <<<NBK, 256, 0, stream>>>(bstart, scr, edata, rowptr2, dis);
    // layer 1
    k_gemm1    <<<1563, 256, 0, stream>>>(flag, x, W1, b1, dis, hbuf);
    k_gather8  <<<4*QBLK8, 256, 0, stream>>>(flag, rowptr2, edata, dis, b1,
                                             (const unsigned*)hbuf, aggB);
    k_bnstats_bf<<<512, 256, 0, stream>>>((const uint2*)aggB, sums + 0, 1);
    // layer 2
    k_gemm64<true, true><<<1563, 256, 0, stream>>>(flag, aggS, W2, b2, g1, bb1,
                                                   sums + 0, dis, hbuf, nullptr);
    k_gather8  <<<4*QBLK8, 256, 0, stream>>>(flag, rowptr2, edata, dis, b2,
                                             (const unsigned*)hbuf, aggB);
    k_bnstats_bf<<<512, 256, 0, stream>>>((const uint2*)aggB, sums + 128, 0);
    // lin1 (+ bn3 stats), y3 bf16 in place over agg2
    k_gemm64<false, false><<<1563, 256, 0, stream>>>(flag, aggS, l1W, l1b, g2, bb2,
                                                     sums + 128, dis, aggS, sums + 256);
    k_final    <<<1563, 256, 0, stream>>>(flag, aggS, g3, bb3, sums + 256, l2W, l2b, d_out);
}

// Round 8
// 534.683 us; speedup vs baseline: 1.8841x; 1.1194x over previous
//
#include <hip/hip_runtime.h>
#include <hip/hip_bf16.h>

// R24: half-split + instruction-diet gather (k_gather9).
// R23's quarter-split fixed traffic (FETCH 297->102MB) but went VALU-bound
// (93% busy): 4 passes quadruple per-edge overhead. gather9:
//  - HALF-split (2 passes, 32 feats/pass, lane loads uint2): halves all
//    per-edge/per-node overhead. 6.4MB half-table partially L2-resident;
//    L3 absorbs misses at the measured 3.3-4.4 TB/s (bounded regression).
//  - zero-pad clamp: scanB zeroes edata[-64..-1] (inside the existing gap
//    before edata, no workspace growth); inactive lanes clamp INDEX to -64
//    -> w15=0 -> coef = +0.0 naturally -> coef cndmask deleted.
//  - 32-bit h indexing (uniform base + unsigned idx), #pragma unroll 2
//    (kills pipeline-rotate movs).
// h stored HALF-MAJOR h[half][node][8 uint2] by k_gemm1/k_gemm64<AGG>.
// aggB stays row-major (node's 16 uint2 = feats 0..63 in order).
// Rest identical to R16: zero-global-atomic counting sort, w15-packed edata,
// h bf16 pre-scaled by dis[src], bf16 intermediates, BN/relu fused in GEMMs.

#define NN 100000
#define NE 3200000
#define INV_N (1.0f/100000.0f)
#define BN_EPS 1e-5f
#define NBK 782            // buckets of 128 nodes
#define NSB 512            // scatter/hist blocks
#define EPB 6250           // edges per scatter/hist block (NSB*EPB == NE)
#define CAPB 6144          // LDS staging per bucket (mean 4092 + 32 sigma)
#define QBLK8 6250         // gather blocks per half (4 waves x 4 nodes)
#define HQW (NN*8)         // uint2 per half-table

static __device__ __forceinline__ float bf2f(unsigned short u) {
    if ((u & 0x7f80u) == 0x7f80u) u = 0;          // inf/NaN -> 0 (input scrub)
    union { unsigned int i; float f; } z; z.i = ((unsigned int)u) << 16; return z.f;
}
static __device__ __forceinline__ float scrubf(float v) {
    return (fabsf(v) < 1e30f) ? v : 0.f;
}
static __device__ __forceinline__ unsigned short f2bf(float v) {
    union { float f; unsigned int i; } z; z.f = v;
    unsigned int lsb = (z.i >> 16) & 1u; z.i += 0x7fffu + lsb;
    return (unsigned short)(z.i >> 16);
}
static __device__ __forceinline__ float ld1(const void* p, size_t i, int f) {
    return f ? scrubf(((const float*)p)[i]) : bf2f(((const unsigned short*)p)[i]);
}
static __device__ __forceinline__ float4 ld4(const void* p, size_t g, int f) {
    if (f) { float4 v = ((const float4*)p)[g];
             return make_float4(scrubf(v.x),scrubf(v.y),scrubf(v.z),scrubf(v.w)); }
    ushort4 u = ((const ushort4*)p)[g];
    return make_float4(bf2f(u.x),bf2f(u.y),bf2f(u.z),bf2f(u.w));
}
static __device__ __forceinline__ int getidx(const int* ei, size_t pos, int i64) {
    return i64 ? ei[2*pos] : ei[pos];
}
static __device__ __forceinline__ float blo(unsigned v) {
    union { unsigned u; float f; } z; z.u = v << 16; return z.f;
}
static __device__ __forceinline__ float bhi(unsigned v) {
    union { unsigned u; float f; } z; z.u = v & 0xffff0000u; return z.f;
}
static __device__ __forceinline__ unsigned w15of(unsigned wu) {
    unsigned lsb = (wu >> 17) & 1u;
    return ((wu + 0xFFFFu + lsb) >> 17) & 0x7fffu;
}

// ---------------- detector + sums zero ----------------
__global__ void k_detect2(const unsigned short* __restrict__ x,
                          const int* __restrict__ ei, int* __restrict__ flag,
                          float* __restrict__ sums) {
    __shared__ int cnt[256];
    int tid = threadIdx.x, c = 0;
    for (int i = tid; i < 1024; i += 256) {
        unsigned short u = x[i];
        int ex = (u >> 7) & 0xff;
        if ((u & 0x7fffu) != 0 && (ex >= 0xB0 || ex <= 0x40)) c++;
    }
    cnt[tid] = c; __syncthreads();
    if (tid == 0) { int t = 0; for (int i = 0; i < 256; ++i) t += cnt[i];
                    flag[0] = (t > 64) ? 1 : 0; }
    if (tid == 1) { int nz = 0; for (int i = 1; i < 64; i += 2) nz |= ei[i];
                    flag[1] = (nz == 0) ? 1 : 0; }
    if (tid < 128) { sums[tid]=0.f; sums[128+tid]=0.f; sums[256+tid]=0.f; }
}

// ================= bucket counting sort (no global atomics) =================

__global__ __launch_bounds__(256) void k_hist(const int* __restrict__ flag,
                                              const int* __restrict__ ei,
                                              int* __restrict__ histmat) {
    __shared__ int hh[NBK];
    const int i64 = flag[1];
    const int blk = blockIdx.x, tid = threadIdx.x;
    for (int b = tid; b < NBK; b += 256) hh[b] = 0;
    __syncthreads();
    const size_t e0 = (size_t)blk * EPB;
    for (int e = tid; e < EPB; e += 256) {
        unsigned d = (unsigned)getidx(ei, NE + e0 + e, i64);
        if (d < NN) atomicAdd(&hh[d >> 7], 1);
    }
    __syncthreads();
    for (int b = tid; b < NBK; b += 256) histmat[blk*NBK + b] = hh[b];
}

// per-bucket column scan across the NSB=512 blocks (exclusive), total -> btot
__global__ __launch_bounds__(256) void k_scanA(int* __restrict__ histmat,
                                               int* __restrict__ btot) {
    __shared__ int sd[256];
    const int b = blockIdx.x, t = threadIdx.x;
    int v0 = histmat[(2*t)*NBK + b];
    int v1 = histmat[(2*t+1)*NBK + b];
    int ts = v0 + v1;
    sd[t] = ts; __syncthreads();
    #pragma unroll
    for (int ofs = 1; ofs < 256; ofs <<= 1) {
        int a = (t >= ofs) ? sd[t-ofs] : 0;
        __syncthreads(); sd[t] += a; __syncthreads();
    }
    int excl = sd[t] - ts;
    histmat[(2*t)*NBK + b]   = excl;
    histmat[(2*t+1)*NBK + b] = excl + v0;
    if (t == 255) btot[b] = sd[255];
}

// + zero the 64-entry pad region just BELOW edata (clamp target for gather9)
__global__ void k_scanB(const int* __restrict__ btot, int* __restrict__ bstart,
                        unsigned* __restrict__ edata) {
    __shared__ int sd[1024];
    int t = threadIdx.x;                 // 1024 threads; NBK=782 < 1024
    int v = (t < NBK) ? btot[t] : 0;
    sd[t] = v; __syncthreads();
    #pragma unroll
    for (int ofs = 1; ofs < 1024; ofs <<= 1) {
        int a = (t >= ofs) ? sd[t-ofs] : 0;
        __syncthreads(); sd[t] += a; __syncthreads();
    }
    if (t <= NBK) bstart[t] = sd[t] - v;   // exclusive; bstart[NBK] = total
    if (t < 64) edata[(int)t - 64] = 0u;   // pad: w15=0 -> coef +0.0
}

__global__ __launch_bounds__(256) void k_scatter(
    const int* __restrict__ flag, const int* __restrict__ ei,
    const void* __restrict__ ew, const int* __restrict__ histmat,
    const int* __restrict__ bstart, int2* __restrict__ scr) {
    __shared__ int cursor[NBK];
    const int f = flag[0], i64 = flag[1];
    const int blk = blockIdx.x, tid = threadIdx.x;
    for (int b = tid; b < NBK; b += 256)
        cursor[b] = histmat[blk*NBK + b] + bstart[b];
    __syncthreads();
    const size_t e0 = (size_t)blk * EPB;
    for (int e = tid; e < EPB; e += 256) {
        unsigned d = (unsigned)getidx(ei, NE + e0 + e, i64);
        if (d >= NN) continue;
        unsigned s = (unsigned)getidx(ei, e0 + e, i64);
        float w = ld1(ew, e0 + e, f);
        if (s >= NN) { s = 0; w = 0.f; }
        int pos = atomicAdd(&cursor[d >> 7], 1);
        scr[pos] = make_int2((int)(((d & 127u) << 17) | s), __float_as_int(w));
    }
}

// fused node-sort + degree over 128-node buckets; w15 staged in LDS;
// coalesced edata write. Overflow (> CAPB, never here): scattered-write path.
__global__ __launch_bounds__(256) void k_sortdeg(
    const int* __restrict__ bstart, const int2* __restrict__ scr,
    unsigned* __restrict__ edata, int* __restrict__ rowptr, float* __restrict__ dis) {
    __shared__ unsigned sp[CAPB];
    __shared__ unsigned out[CAPB];
    __shared__ unsigned short sww[CAPB];
    __shared__ int cnt[128], scn[128], cur[128];
    __shared__ float degf[128];
    const int b = blockIdx.x, tid = threadIdx.x;
    const int node0 = b * 128;
    const int r0 = bstart[b], r1 = bstart[b+1], n = r1 - r0;
    const bool fit = (n <= CAPB);

    if (tid < 128) { cnt[tid] = 0; degf[tid] = 1.0f; }
    __syncthreads();
    if (fit) {
        for (int j = tid; j < n; j += 256) {
            int2 m = scr[r0 + j];
            sp[j] = (unsigned)m.x;
            sww[j] = (unsigned short)w15of((unsigned)m.y);
            int l = (m.x >> 17) & 127;
            atomicAdd(&cnt[l], 1);
            atomicAdd(&degf[l], __int_as_float(m.y));
        }
    } else {
        for (int j = tid; j < n; j += 256) {
            int2 m = scr[r0 + j];
            int l = (m.x >> 17) & 127;
            atomicAdd(&cnt[l], 1);
            atomicAdd(&degf[l], __int_as_float(m.y));
        }
    }
    __syncthreads();
    if (tid < 128) scn[tid] = cnt[tid];
    __syncthreads();
    #pragma unroll
    for (int ofs = 1; ofs < 128; ofs <<= 1) {
        int a = 0;
        if (tid < 128 && tid >= ofs) a = scn[tid - ofs];
        __syncthreads();
        if (tid < 128) scn[tid] += a;
        __syncthreads();
    }
    if (tid < 128) {
        int excl = scn[tid] - cnt[tid];
        cur[tid] = excl;
        int node = node0 + tid;
        if (node <= NN) rowptr[node] = r0 + excl;
        if (node <  NN) dis[node] = rsqrtf(fmaxf(degf[tid], 1e-12f));
    }
    __syncthreads();
    if (fit) {
        for (int j = tid; j < n; j += 256) {
            unsigned p = sp[j];
            int l = (p >> 17) & 127;
            int pos = atomicAdd(&cur[l], 1);
            out[pos] = (p & 0x1ffffu) | ((unsigned)sww[j] << 17);
        }
        __syncthreads();
        for (int j = tid; j < n; j += 256)           // coalesced linear write
            edata[r0 + j] = out[j];
    } else {
        for (int j = tid; j < n; j += 256) {
            int2 m = scr[r0 + j];
            int l = (m.x >> 17) & 127;
            int pos = atomicAdd(&cur[l], 1);
            edata[r0 + pos] = ((unsigned)m.x & 0x1ffffu) | (w15of((unsigned)m.y) << 17);
        }
    }
}

// gather: half = blockIdx/QBLK8 (blockIdx-major). Wave = 8 edge-slots (g) x
// 8 lanes (l); lane loads uint2 (4 feats: half*32 + 4l..4l+3); 4 nodes
// concurrent; 2-deep pipeline (edata 2 ahead, h 1 ahead). Inactive lanes
// clamp INDEX to -64 (zeroed pad -> w15=0 -> coef +0.0, no coef select).
// Epilogue: slot-reduce, self + bias, slot-0 writes uint2 per node.
__global__ __launch_bounds__(256, 4) void k_gather9(
    const int* __restrict__ flag, const int* __restrict__ rowptr,
    const unsigned* __restrict__ edata, const float* __restrict__ dis,
    const void* __restrict__ bias, const uint2* __restrict__ hq,
    uint2* __restrict__ aggB) {
    const int f = flag[0];
    const int half = blockIdx.x / QBLK8;                   // 0..1, major order
    const int bq   = blockIdx.x % QBLK8;
    const int node0 = bq * 16 + (threadIdx.x >> 6) * 4;
    const int lane = threadIdx.x & 63;
    const int g = lane >> 3;                               // edge slot 0..7
    const unsigned l = (unsigned)(lane & 7);               // uint2 within half
    const uint2* __restrict__ hb = hq + (size_t)half * HQW;

    const int r0 = rowptr[node0+0], r1 = rowptr[node0+1];
    const int r2 = rowptr[node0+2], r3 = rowptr[node0+3];
    const int r4 = rowptr[node0+4];
    const float d0 = dis[node0+0], d1 = dis[node0+1];
    const float d2v = dis[node0+2], d3 = dis[node0+3];

    int mx = max(max(r1-r0, r2-r1), max(r3-r2, r4-r3));
    const int nsteps = (mx + 7) >> 3;

    float a00=0,a01=0,a02=0,a03=0;   // node0+0, feats 4l..4l+3
    float a10=0,a11=0,a12=0,a13=0;
    float a20=0,a21=0,a22=0,a23=0;
    float a30=0,a31=0,a32=0,a33=0;

    // step-0 edata + h + coef, step-1 edata (2-ahead). Clamp idx -> -64.
    int ia0 = r0 + g, ia1 = r1 + g, ia2 = r2 + g, ia3 = r3 + g;
    unsigned m0 = edata[ia0 < r1 ? ia0 : -64];
    unsigned m1 = edata[ia1 < r2 ? ia1 : -64];
    unsigned m2 = edata[ia2 < r3 ? ia2 : -64];
    unsigned m3 = edata[ia3 < r4 ? ia3 : -64];
    uint2 w0 = hb[(m0 & 0x1ffffu)*8u + l];
    uint2 w1 = hb[(m1 & 0x1ffffu)*8u + l];
    uint2 w2 = hb[(m2 & 0x1ffffu)*8u + l];
    uint2 w3 = hb[(m3 & 0x1ffffu)*8u + l];
    float c0 = __int_as_float((int)(m0 & 0xFFFE0000u)) * d0;
    float c1 = __int_as_float((int)(m1 & 0xFFFE0000u)) * d1;
    float c2 = __int_as_float((int)(m2 & 0xFFFE0000u)) * d2v;
    float c3 = __int_as_float((int)(m3 & 0xFFFE0000u)) * d3;
    int ib0 = ia0 + 8, ib1 = ia1 + 8, ib2 = ia2 + 8, ib3 = ia3 + 8;
    unsigned n0 = edata[ib0 < r1 ? ib0 : -64];
    unsigned n1 = edata[ib1 < r2 ? ib1 : -64];
    unsigned n2 = edata[ib2 < r3 ? ib2 : -64];
    unsigned n3 = edata[ib3 < r4 ? ib3 : -64];

    #pragma unroll 2
    for (int s = 0; s < nsteps; ++s) {
        // h for step s+1 (n* loaded one iteration ago)
        uint2 x0 = hb[(n0 & 0x1ffffu)*8u + l];
        uint2 x1 = hb[(n1 & 0x1ffffu)*8u + l];
        uint2 x2 = hb[(n2 & 0x1ffffu)*8u + l];
        uint2 x3 = hb[(n3 & 0x1ffffu)*8u + l];
        float e0 = __int_as_float((int)(n0 & 0xFFFE0000u)) * d0;
        float e1 = __int_as_float((int)(n1 & 0xFFFE0000u)) * d1;
        float e2 = __int_as_float((int)(n2 & 0xFFFE0000u)) * d2v;
        float e3 = __int_as_float((int)(n3 & 0xFFFE0000u)) * d3;
        // edata for step s+2
        ib0 += 8; ib1 += 8; ib2 += 8; ib3 += 8;
        n0 = edata[ib0 < r1 ? ib0 : -64];
        n1 = edata[ib1 < r2 ? ib1 : -64];
        n2 = edata[ib2 < r3 ? ib2 : -64];
        n3 = edata[ib3 < r4 ? ib3 : -64];
        // FMA step s (w*/c* issued one iteration ago)
        a00 = fmaf(c0, blo(w0.x), a00); a01 = fmaf(c0, bhi(w0.x), a01);
        a02 = fmaf(c0, blo(w0.y), a02); a03 = fmaf(c0, bhi(w0.y), a03);
        a10 = fmaf(c1, blo(w1.x), a10); a11 = fmaf(c1, bhi(w1.x), a11);
        a12 = fmaf(c1, blo(w1.y), a12); a13 = fmaf(c1, bhi(w1.y), a13);
        a20 = fmaf(c2, blo(w2.x), a20); a21 = fmaf(c2, bhi(w2.x), a21);
        a22 = fmaf(c2, blo(w2.y), a22); a23 = fmaf(c2, bhi(w2.y), a23);
        a30 = fmaf(c3, blo(w3.x), a30); a31 = fmaf(c3, bhi(w3.x), a31);
        a32 = fmaf(c3, blo(w3.y), a32); a33 = fmaf(c3, bhi(w3.y), a33);
        // rotate (renamed away by unroll)
        w0 = x0; w1 = x1; w2 = x2; w3 = x3;
        c0 = e0; c1 = e1; c2 = e2; c3 = e3;
    }

    // reduce across the 8 edge slots (lane strides 8,16,32)
    a00 += __shfl_xor(a00, 8); a00 += __shfl_xor(a00, 16); a00 += __shfl_xor(a00, 32);
    a01 += __shfl_xor(a01, 8); a01 += __shfl_xor(a01, 16); a01 += __shfl_xor(a01, 32);
    a02 += __shfl_xor(a02, 8); a02 += __shfl_xor(a02, 16); a02 += __shfl_xor(a02, 32);
    a03 += __shfl_xor(a03, 8); a03 += __shfl_xor(a03, 16); a03 += __shfl_xor(a03, 32);
    a10 += __shfl_xor(a10, 8); a10 += __shfl_xor(a10, 16); a10 += __shfl_xor(a10, 32);
    a11 += __shfl_xor(a11, 8); a11 += __shfl_xor(a11, 16); a11 += __shfl_xor(a11, 32);
    a12 += __shfl_xor(a12, 8); a12 += __shfl_xor(a12, 16); a12 += __shfl_xor(a12, 32);
    a13 += __shfl_xor(a13, 8); a13 += __shfl_xor(a13, 16); a13 += __shfl_xor(a13, 32);
    a20 += __shfl_xor(a20, 8); a20 += __shfl_xor(a20, 16); a20 += __shfl_xor(a20, 32);
    a21 += __shfl_xor(a21, 8); a21 += __shfl_xor(a21, 16); a21 += __shfl_xor(a21, 32);
    a22 += __shfl_xor(a22, 8); a22 += __shfl_xor(a22, 16); a22 += __shfl_xor(a22, 32);
    a23 += __shfl_xor(a23, 8); a23 += __shfl_xor(a23, 16); a23 += __shfl_xor(a23, 32);
    a30 += __shfl_xor(a30, 8); a30 += __shfl_xor(a30, 16); a30 += __shfl_xor(a30, 32);
    a31 += __shfl_xor(a31, 8); a31 += __shfl_xor(a31, 16); a31 += __shfl_xor(a31, 32);
    a32 += __shfl_xor(a32, 8); a32 += __shfl_xor(a32, 16); a32 += __shfl_xor(a32, 32);
    a33 += __shfl_xor(a33, 8); a33 += __shfl_xor(a33, 16); a33 += __shfl_xor(a33, 32);

    if (g == 0) {
        const int fb = half*32 + (int)l*4;
        const float b0 = ld1(bias, fb+0, f), b1 = ld1(bias, fb+1, f);
        const float b2 = ld1(bias, fb+2, f), b3 = ld1(bias, fb+3, f);
        {   uint2 hv = hb[(size_t)(node0+0)*8 + l];
            float s0=a00+b0+d0*blo(hv.x), s1=a01+b1+d0*bhi(hv.x);
            float s2=a02+b2+d0*blo(hv.y), s3=a03+b3+d0*bhi(hv.y);
            aggB[(size_t)(node0+0)*16 + half*8 + l] = make_uint2(
                (unsigned)f2bf(s0)|((unsigned)f2bf(s1)<<16),
                (unsigned)f2bf(s2)|((unsigned)f2bf(s3)<<16)); }
        {   uint2 hv = hb[(size_t)(node0+1)*8 + l];
            float s0=a10+b0+d1*blo(hv.x), s1=a11+b1+d1*bhi(hv.x);
            float s2=a12+b2+d1*blo(hv.y), s3=a13+b3+d1*bhi(hv.y);
            aggB[(size_t)(node0+1)*16 + half*8 + l] = make_uint2(
                (unsigned)f2bf(s0)|((unsigned)f2bf(s1)<<16),
                (unsigned)f2bf(s2)|((unsigned)f2bf(s3)<<16)); }
        {   uint2 hv = hb[(size_t)(node0+2)*8 + l];
            float s0=a20+b0+d2v*blo(hv.x), s1=a21+b1+d2v*bhi(hv.x);
            float s2=a22+b2+d2v*blo(hv.y), s3=a23+b3+d2v*bhi(hv.y);
            aggB[(size_t)(node0+2)*16 + half*8 + l] = make_uint2(
                (unsigned)f2bf(s0)|((unsigned)f2bf(s1)<<16),
                (unsigned)f2bf(s2)|((unsigned)f2bf(s3)<<16)); }
        {   uint2 hv = hb[(size_t)(node0+3)*8 + l];
            float s0=a30+b0+d3*blo(hv.x), s1=a31+b1+d3*bhi(hv.x);
            float s2=a32+b2+d3*blo(hv.y), s3=a33+b3+d3*bhi(hv.y);
            aggB[(size_t)(node0+3)*16 + half*8 + l] = make_uint2(
                (unsigned)f2bf(s0)|((unsigned)f2bf(s1)<<16),
                (unsigned)f2bf(s2)|((unsigned)f2bf(s3)<<16)); }
    }
}

// ================= dense kernels =================

// h_out written HALF-MAJOR: uint2 at h2[(half*NN + r)*8 + (tc&31)/4]
__global__ __launch_bounds__(256) void k_gemm1(
    const int* __restrict__ flag, const void* __restrict__ x,
    const void* __restrict__ W, const void* __restrict__ bias,
    const float* __restrict__ dis, unsigned short* __restrict__ h_out) {
    __shared__ __align__(16) float ws[128*64];
    __shared__ __align__(16) float xs[64*64];
    const int f = flag[0];
    const int tid = threadIdx.x;
    const int rowbase = blockIdx.x * 64;
    #pragma unroll
    for (int it = 0; it < 8; ++it) {
        int g = it*256 + tid;
        float4 v = ld4(W, g, f);
        int b = g*4;
        ws[b]=v.x; ws[b+1]=v.y; ws[b+2]=v.z; ws[b+3]=v.w;
    }
    const int tr = (tid >> 4) << 2;
    const int tc = (tid & 15) << 2;
    const int row = tid & 63;
    const int grow = rowbase + row;
    const bool valid = grow < NN;
    float acc[4][4] = {};
    for (int half = 0; half < 2; ++half) {
        __syncthreads();
        #pragma unroll
        for (int it = 0; it < 4; ++it) {
            int f4 = (tid >> 6) + it*4;
            int kl = f4*4;
            float4 v = make_float4(0,0,0,0);
            if (valid) v = ld4(x, (size_t)grow*32 + half*16 + f4, f);
            xs[(kl+0)*64+row]=v.x; xs[(kl+1)*64+row]=v.y;
            xs[(kl+2)*64+row]=v.z; xs[(kl+3)*64+row]=v.w;
        }
        __syncthreads();
        #pragma unroll 8
        for (int k = 0; k < 64; ++k) {
            const float4 av = *(const float4*)&xs[k*64 + tr];
            const float4 wv = *(const float4*)&ws[(half*64 + k)*64 + tc];
            const float aa[4] = {av.x, av.y, av.z, av.w};
            const float ww[4] = {wv.x, wv.y, wv.z, wv.w};
            #pragma unroll
            for (int i = 0; i < 4; ++i)
                #pragma unroll
                for (int j = 0; j < 4; ++j)
                    acc[i][j] = fmaf(aa[i], ww[j], acc[i][j]);
        }
    }
    uint2* __restrict__ ho = (uint2*)h_out;
    const int hh = tc >> 5, uu = (tc & 31) >> 2;
    #pragma unroll
    for (int i = 0; i < 4; ++i) {
        int r = rowbase + tr + i;
        if (r < NN) {
            float hm = dis[r];
            unsigned p0 = (unsigned)f2bf(acc[i][0]*hm) | ((unsigned)f2bf(acc[i][1]*hm) << 16);
            unsigned p1 = (unsigned)f2bf(acc[i][2]*hm) | ((unsigned)f2bf(acc[i][3]*hm) << 16);
            ho[((size_t)hh*NN + r)*8 + uu] = make_uint2(p0, p1);
        }
    }
}

// BN column stats over bf16 tensor (uint2 = 4 features); 512 blocks
__global__ __launch_bounds__(256) void k_bnstats_bf(const uint2* __restrict__ src,
                                                    float* __restrict__ sumout, int relu) {
    const int tid = threadIdx.x;
    float s0=0,s1=0,s2=0,s3=0, q0=0,q1=0,q2=0,q3=0;
    for (int g = blockIdx.x*256 + tid; g < NN*16; g += 512*256) {
        uint2 u = src[g];
        float vx = blo(u.x), vy = bhi(u.x), vz = blo(u.y), vw = bhi(u.y);
        if (relu) { vx=fmaxf(vx,0.f); vy=fmaxf(vy,0.f);
                    vz=fmaxf(vz,0.f); vw=fmaxf(vw,0.f); }
        s0+=vx; q0+=vx*vx; s1+=vy; q1+=vy*vy;
        s2+=vz; q2+=vz*vz; s3+=vw; q3+=vw*vw;
    }
    __shared__ float ls[1024], lq[1024];
    ls[tid*4+0]=s0; ls[tid*4+1]=s1; ls[tid*4+2]=s2; ls[tid*4+3]=s3;
    lq[tid*4+0]=q0; lq[tid*4+1]=q1; lq[tid*4+2]=q2; lq[tid*4+3]=q3;
    __syncthreads();
    if (tid < 64) {
        int grp = tid >> 2, k = tid & 3;
        float s = 0.f, q = 0.f;
        #pragma unroll
        for (int m = 0; m < 16; ++m) {
            int idx = (grp + 16*m)*4 + k;
            s += ls[idx]; q += lq[idx];
        }
        unsafeAtomicAdd(&sumout[tid], s);
        unsafeAtomicAdd(&sumout[64+tid], q);
    }
}

// 64x64 GEMM, bf16 input (row-major) with fused BN (+relu).
// AGG=true: output half-major (feeds k_gather9); else row-major + stats.
template<bool RELU, bool AGG>
__global__ __launch_bounds__(256) void k_gemm64(
    const int* __restrict__ flag, const unsigned short* __restrict__ in,
    const void* __restrict__ W, const void* __restrict__ bias,
    const void* __restrict__ g, const void* __restrict__ bb,
    const float* __restrict__ insums, const float* __restrict__ dis,
    unsigned short* __restrict__ out_bf, float* __restrict__ outsums) {
    __shared__ __align__(16) float ws[64*64];
    __shared__ __align__(16) float xs[64*64];
    __shared__ float sc[64], sh[64];
    const int f = flag[0];
    const int tid = threadIdx.x;
    const int rowbase = blockIdx.x * 64;
    if (tid < 64) {
        float mean = insums[tid] * INV_N;
        float var  = fmaxf(insums[64+tid] * INV_N - mean*mean, 0.f);
        float s = ld1(g, tid, f) * rsqrtf(var + BN_EPS);
        sc[tid] = s;
        sh[tid] = ld1(bb, tid, f) - mean*s;
    }
    #pragma unroll
    for (int it = 0; it < 4; ++it) {
        int gi = it*256 + tid;
        float4 v = ld4(W, gi, f);
        int b = gi*4;
        ws[b]=v.x; ws[b+1]=v.y; ws[b+2]=v.z; ws[b+3]=v.w;
    }
    __syncthreads();
    {
        int row = tid & 63;
        int grow = rowbase + row;
        bool valid = grow < NN;
        #pragma unroll
        for (int it = 0; it < 4; ++it) {
            int f4 = (tid >> 6) + it*4;
            int k = f4*4;
            float a0=0,a1=0,a2=0,a3=0;
            if (valid) {
                ushort4 u = *(const ushort4*)&in[(size_t)grow*64 + k];
                a0=bf2f(u.x); a1=bf2f(u.y); a2=bf2f(u.z); a3=bf2f(u.w);
            }
            if (RELU) { a0=fmaxf(a0,0.f); a1=fmaxf(a1,0.f); a2=fmaxf(a2,0.f); a3=fmaxf(a3,0.f); }
            a0 = a0*sc[k+0]+sh[k+0]; a1 = a1*sc[k+1]+sh[k+1];
            a2 = a2*sc[k+2]+sh[k+2]; a3 = a3*sc[k+3]+sh[k+3];
            xs[(k+0)*64+row]=a0; xs[(k+1)*64+row]=a1;
            xs[(k+2)*64+row]=a2; xs[(k+3)*64+row]=a3;
        }
    }
    __syncthreads();
    const int tr = (tid >> 4) << 2;
    const int tc = (tid & 15) << 2;
    float acc[4][4] = {};
    #pragma unroll 8
    for (int k = 0; k < 64; ++k) {
        const float4 av = *(const float4*)&xs[k*64 + tr];
        const float4 wv = *(const float4*)&ws[k*64 + tc];
        const float aa[4] = {av.x, av.y, av.z, av.w};
        const float ww[4] = {wv.x, wv.y, wv.z, wv.w};
        #pragma unroll
        for (int i = 0; i < 4; ++i)
            #pragma unroll
            for (int j = 0; j < 4; ++j)
                acc[i][j] = fmaf(aa[i], ww[j], acc[i][j]);
    }
    float bc[4];
    #pragma unroll
    for (int j = 0; j < 4; ++j) bc[j] = ld1(bias, tc+j, f);
    if (AGG) {
        uint2* __restrict__ ho = (uint2*)out_bf;
        const int hh = tc >> 5, uu = (tc & 31) >> 2;
        #pragma unroll
        for (int i = 0; i < 4; ++i) {
            int r = rowbase + tr + i;
            if (r < NN) {
                float hm = dis[r];
                unsigned p0 = (unsigned)f2bf(acc[i][0]*hm) | ((unsigned)f2bf(acc[i][1]*hm) << 16);
                unsigned p1 = (unsigned)f2bf(acc[i][2]*hm) | ((unsigned)f2bf(acc[i][3]*hm) << 16);
                ho[((size_t)hh*NN + r)*8 + uu] = make_uint2(p0, p1);
            }
        }
    } else {
        float ps[4] = {0,0,0,0}, pq[4] = {0,0,0,0};
        #pragma unroll
        for (int i = 0; i < 4; ++i) {
            int r = rowbase + tr + i;
            if (r < NN) {
                float y0 = acc[i][0]+bc[0], y1 = acc[i][1]+bc[1];
                float y2 = acc[i][2]+bc[2], y3 = acc[i][3]+bc[3];
                *(ushort4*)&out_bf[(size_t)r*64 + tc] =
                    make_ushort4(f2bf(y0), f2bf(y1), f2bf(y2), f2bf(y3));
                ps[0]+=y0; ps[1]+=y1; ps[2]+=y2; ps[3]+=y3;
                pq[0]+=y0*y0; pq[1]+=y1*y1; pq[2]+=y2*y2; pq[3]+=y3*y3;
            }
        }
        __syncthreads();
        int grp = tid >> 4;
        #pragma unroll
        for (int j = 0; j < 4; ++j) { xs[grp*64 + tc+j] = ps[j]; ws[grp*64 + tc+j] = pq[j]; }
        __syncthreads();
        if (tid < 64) {
            float s = 0.f, q = 0.f;
            #pragma unroll
            for (int g2 = 0; g2 < 16; ++g2) { s += xs[g2*64+tid]; q += ws[g2*64+tid]; }
            unsafeAtomicAdd(&outsums[tid], s);
            unsafeAtomicAdd(&outsums[64+tid], q);
        }
    }
}

// final: out = bn3(y3_bf16) @ lin2_W + lin2_b
__global__ __launch_bounds__(256) void k_final(
    const int* __restrict__ flag, const unsigned short* __restrict__ y3,
    const void* __restrict__ g, const void* __restrict__ bb,
    const float* __restrict__ sums, const void* __restrict__ w2,
    const void* __restrict__ b2, void* __restrict__ out) {
    __shared__ __align__(16) float tile[64*64];
    __shared__ float wp[64], tv[64];
    const int f = flag[0];
    const int tid = threadIdx.x;
    const int base = blockIdx.x * 64;
    if (tid < 64) {
        float mean = sums[tid] * INV_N;
        float var  = fmaxf(sums[64+tid] * INV_N - mean*mean, 0.f);
        float s = ld1(g, tid, f) * rsqrtf(var + BN_EPS);
        float t = ld1(bb, tid, f) - mean*s;
        float w = ld1(w2, tid, f);
        wp[tid] = s*w; tv[tid] = t*w;
    }
    #pragma unroll
    for (int it = 0; it < 4; ++it) {
        int i4 = it*256 + tid;
        int row = i4 >> 4, c4 = (i4 & 15)*4;
        float4 v = make_float4(0,0,0,0);
        if (base + row < NN) {
            ushort4 u = *(const ushort4*)&y3[(size_t)(base+row)*64 + c4];
            v = make_float4(bf2f(u.x), bf2f(u.y), bf2f(u.z), bf2f(u.w));
        }
        *(float4*)&tile[row*64 + c4] = v;
    }
    __syncthreads();
    if (tid < 64 && base + tid < NN) {
        float a = ld1(b2, 0, f);
        #pragma unroll
        for (int c = 0; c < 64; ++c) a += tv[c];
        #pragma unroll
        for (int cc = 0; cc < 64; ++cc) {
            int c = (cc + tid) & 63;
            a += tile[tid*64 + c] * wp[c];
        }
        if (f) ((float*)out)[base + tid] = a;
        else   ((unsigned short*)out)[base + tid] = f2bf(a);
    }
}

extern "C" void kernel_launch(void* const* d_in, const int* in_sizes, int n_in,
                              void* d_out, int out_size, void* d_ws, size_t ws_size,
                              hipStream_t stream) {
    const unsigned short* x = (const unsigned short*)d_in[0];
    const void* ew  = d_in[1];
    const void* W1  = d_in[2];
    const void* b1  = d_in[3];
    const void* W2  = d_in[4];
    const void* b2  = d_in[5];
    const void* l1W = d_in[6];
    const void* l1b = d_in[7];
    const void* l2W = d_in[8];
    const void* l2b = d_in[9];
    const void* g1  = d_in[10];
    const void* bb1 = d_in[11];
    const void* g2  = d_in[12];
    const void* bb2 = d_in[13];
    const void* g3  = d_in[14];
    const void* bb3 = d_in[15];
    const int* eidx = (const int*)d_in[16];

    // layout (float idx): flag 0, sums 16, dis 400;
    // region 100400..6500400: scr(int2) during preprocessing, then aggB (bf16)
    // hbuf(bf16, half-major) 6500400..9700400, histmat/rowptr 9700400,
    // btot 10500656, bstart 10502224 (ends 10503007; gap 10503008..10503791
    // holds the 64-word zero pad at edata[-64]), edata 10503792..13703792.
    int*   flag = (int*)d_ws;
    float* wsf  = (float*)d_ws;
    float* sums = wsf + 16;
    float* dis  = wsf + 400;
    uint2*          aggB = (uint2*)(wsf + 100400);
    unsigned short* aggS = (unsigned short*)(wsf + 100400);
    unsigned short* hbuf = (unsigned short*)(wsf + 6500400);
    int*      histmat = (int*)(wsf + 9700400);
    int*      rowptr2 = histmat;
    int*      btot    = (int*)(wsf + 10500656);
    int*      bstart  = (int*)(wsf + 10502224);
    unsigned* edata   = (unsigned*)(wsf + 10503792);
    int2*     scr     = (int2*)(wsf + 100400);
    const size_t NEED = (size_t)13703792 * 4;
    if (ws_size < NEED) return;

    k_detect2  <<<1, 256, 0, stream>>>(x, eidx, flag, sums);
    k_hist     <<<NSB, 256, 0, stream>>>(flag, eidx, histmat);
    k_scanA    <<<NBK, 256, 0, stream>>>(histmat, btot);
    k_scanB    <<<1, 1024, 0, stream>>>(btot, bstart, edata);
    k_scatter  <<<NSB, 256, 0, stream>>>(flag, eidx, ew, histmat, bstart, scr);
    k_sortdeg  <<<NBK, 256, 0, stream>>>(bstart, scr, edata, rowptr2, dis);
    // layer 1
    k_gemm1    <<<1563, 256, 0, stream>>>(flag, x, W1, b1, dis, hbuf);
    k_gather9  <<<2*QBLK8, 256, 0, stream>>>(flag, rowptr2, edata, dis, b1,
                                             (const uint2*)hbuf, aggB);
    k_bnstats_bf<<<512, 256, 0, stream>>>((const uint2*)aggB, sums + 0, 1);
    // layer 2
    k_gemm64<true, true><<<1563, 256, 0, stream>>>(flag, aggS, W2, b2, g1, bb1,
                                                   sums + 0, dis, hbuf, nullptr);
    k_gather9  <<<2*QBLK8, 256, 0, stream>>>(flag, rowptr2, edata, dis, b2,
                                             (const uint2*)hbuf, aggB);
    k_bnstats_bf<<<512, 256, 0, stream>>>((const uint2*)aggB, sums + 128, 0);
    // lin1 (+ bn3 stats), y3 bf16 in place over agg2
    k_gemm64<false, false><<<1563, 256, 0, stream>>>(flag, aggS, l1W, l1b, g2, bb2,
                                                     sums + 128, dis, aggS, sums + 256);
    k_final    <<<1563, 256, 0, stream>>>(flag, aggS, g3, bb3, sums + 256, l2W, l2b, d_out);
}